// Round 10
// baseline (167.330 us; speedup 1.0000x reference)
//
#include <hip/hip_runtime.h>

// Sizes (fixed by the problem)
#define BB 4
#define CC 256
#define HH 128
#define WW 128
#define HP 64          // pooled H, W
#define NP 4096        // HP*HP tokens per batch

#define L2E 1.4426950408889634f

typedef __attribute__((ext_vector_type(4)))  float f32x4;
typedef __attribute__((ext_vector_type(16))) float f32x16;
typedef __attribute__((ext_vector_type(8)))  short bf16x8;       // 8 bf16 in 4 VGPRs
typedef __attribute__((ext_vector_type(4)))  unsigned int u32x4;

// 2^x via v_exp_f32 (native). NOT __exp2f: that name collides with glibc macros.
static __device__ __forceinline__ float exp2fast(float x) {
    return __builtin_amdgcn_exp2f(x);
}

// float -> bf16 bits, round-to-nearest-even (finite inputs only).
// NOTE: R9 used __bf16 casts here; that changed rounding (absmax 0.0156->0.078).
// This bit-trick is the reference-matching RNE — keep it.
static __device__ __forceinline__ unsigned short f2bf(float f) {
    unsigned int u = __float_as_uint(f);
    u = (u + 0x7FFFu + ((u >> 16) & 1u)) >> 16;
    return (unsigned short)u;
}
static __device__ __forceinline__ unsigned int pk2(float a, float b) {
    return (unsigned int)f2bf(a) | ((unsigned int)f2bf(b) << 16);
}
// in-place half-swap between two VGPRs: a' = {a.lo, b.lo}, b' = {a.hi, b.hi}
// (verified lane-exact vs shfl_xor(..,32) select logic in R8/R9)
#define PERMSWAP(a, b) asm volatile("v_permlane32_swap_b32 %0, %1" : "+v"(a), "+v"(b))

// ---------------------------------------------------------------------------
// Fragment-ordered workspace layouts (all bf16, per batch):
//   Q2[qtile(128)][f(2)][q(32)][hi(2)][e(8)]   : chan = f*16 + hi*8 + e, row = qtile*32+q
//   K2[kchunk(128)][f(2)][k(32)][hi(2)][e(8)]  : same, row = key
//   V2[kc(128)][w2(2)][ctg(8)][q(32)][hi(2)][e(8)] : c = ctg*32+q, key = kc*32+w2*16+hi*8+e
// A wave's 16B/lane fragment load covers one contiguous 1KB block.
// ---------------------------------------------------------------------------

// ---------------------------------------------------------------------------
// K1: 2x2 average pool. x[b][c][128][128] -> xp[b][c][64*64]
// ---------------------------------------------------------------------------
__global__ __launch_bounds__(256) void pool_kernel(const float* __restrict__ x,
                                                   float* __restrict__ xp) {
    int tid = blockIdx.x * 256 + threadIdx.x;      // B*C*NP threads
    int wp = tid & 63;
    int hp = (tid >> 6) & 63;
    int bc = tid >> 12;
    const float* src = x + (size_t)bc * (HH * WW) + (2 * hp) * WW + 2 * wp;
    float2 a = *(const float2*)(src);
    float2 b = *(const float2*)(src + WW);
    xp[tid] = 0.25f * (a.x + a.y + b.x + b.y);
}

// ---------------------------------------------------------------------------
// K2: fused QKV projection GEMM (fp32 math), bf16 outputs in fragment order.
// Q pre-scaled by log2(e) so flash softmax uses exp2 directly.
// ---------------------------------------------------------------------------
__global__ __launch_bounds__(256) void proj_kernel(const float* __restrict__ xp,
    const float* __restrict__ wq, const float* __restrict__ bq,
    const float* __restrict__ wk, const float* __restrict__ bk,
    const float* __restrict__ wv, const float* __restrict__ bv,
    unsigned short* __restrict__ qarr, unsigned short* __restrict__ karr,
    unsigned short* __restrict__ varr) {
    __shared__ float lx[32][64];    // [c][n]
    __shared__ float lwT[32][64];   // [c][o]
    int t = threadIdx.x;
    int ot = blockIdx.x % 5;
    int nt = (blockIdx.x / 5) & 63;
    int b  = blockIdx.x / 320;

    float acc[4][4];
    #pragma unroll
    for (int i = 0; i < 4; i++)
        #pragma unroll
        for (int j = 0; j < 4; j++) acc[i][j] = 0.f;

    int n0 = (t & 15) * 4;
    int o0 = (t >> 4) * 4;

    int o_l = t >> 2;               // 0..63 weight row
    int og  = ot * 64 + o_l;
    const float* wrow;
    if (og < 32)      wrow = wq + og * CC;
    else if (og < 64) wrow = wk + (og - 32) * CC;
    else              wrow = wv + (og - 64) * CC;
    int c8 = (t & 3) * 8;

    const float* xbase = xp + (size_t)b * CC * NP + nt * 64;
    int cl = t >> 3;                // 0..31
    int nl = (t & 7) * 8;

    for (int c0 = 0; c0 < 256; c0 += 32) {
        const float* xg = xbase + (size_t)(c0 + cl) * NP + nl;
        float4 v0 = *(const float4*)(xg);
        float4 v1 = *(const float4*)(xg + 4);
        float4 w0 = *(const float4*)(wrow + c0 + c8);
        float4 w1 = *(const float4*)(wrow + c0 + c8 + 4);
        __syncthreads();
        *(float4*)&lx[cl][nl]     = v0;
        *(float4*)&lx[cl][nl + 4] = v1;
        lwT[c8 + 0][o_l] = w0.x; lwT[c8 + 1][o_l] = w0.y;
        lwT[c8 + 2][o_l] = w0.z; lwT[c8 + 3][o_l] = w0.w;
        lwT[c8 + 4][o_l] = w1.x; lwT[c8 + 5][o_l] = w1.y;
        lwT[c8 + 6][o_l] = w1.z; lwT[c8 + 7][o_l] = w1.w;
        __syncthreads();
        #pragma unroll
        for (int cc = 0; cc < 32; cc += 4) {
            float4 xv[4], wv4[4];
            #pragma unroll
            for (int ci = 0; ci < 4; ci++) {
                xv[ci]  = *(const float4*)&lx[cc + ci][n0];
                wv4[ci] = *(const float4*)&lwT[cc + ci][o0];
            }
            #pragma unroll
            for (int ci = 0; ci < 4; ci++) {
                float xn[4] = {xv[ci].x, xv[ci].y, xv[ci].z, xv[ci].w};
                float wo[4] = {wv4[ci].x, wv4[ci].y, wv4[ci].z, wv4[ci].w};
                #pragma unroll
                for (int ni = 0; ni < 4; ni++)
                    #pragma unroll
                    for (int oi = 0; oi < 4; oi++)
                        acc[ni][oi] += xn[ni] * wo[oi];
            }
        }
    }

    float bias[4];
    #pragma unroll
    for (int oi = 0; oi < 4; oi++) {
        int o = ot * 64 + o0 + oi;
        bias[oi] = (o < 32) ? bq[o] : (o < 64) ? bk[o - 32] : bv[o - 64];
    }

    if (ot == 0) {
        // Q (o0<32) or K (o0>=32); wave-uniform since o0 = 16*(t>>6)+...
        bool isQ = (o0 < 32);
        int o2 = isQ ? o0 : (o0 - 32);
        int f  = o2 >> 4;
        int hi = (o2 >> 3) & 1;
        int e0 = o2 & 7;
        unsigned short* arr = (isQ ? qarr : karr) + (size_t)b * (NP * 32);
        float qs = isQ ? L2E : 1.0f;   // q pre-scaled for exp2 softmax
        #pragma unroll
        for (int ni = 0; ni < 4; ni++) {
            int n = nt * 64 + n0 + ni;
            ushort4 r;
            r.x = f2bf((acc[ni][0] + bias[0]) * qs);
            r.y = f2bf((acc[ni][1] + bias[1]) * qs);
            r.z = f2bf((acc[ni][2] + bias[2]) * qs);
            r.w = f2bf((acc[ni][3] + bias[3]) * qs);
            size_t idx = (((size_t)(n >> 5) * 2 + f) * 32 + (n & 31)) * 16 + hi * 8 + e0;
            *(ushort4*)(arr + idx) = r;
        }
    } else {
        int n0g = nt * 64 + n0;
        int kc = n0g >> 5, w2 = (n0g >> 4) & 1, hi = (n0g >> 3) & 1, e0 = n0g & 7;
        unsigned short* vb = varr + (size_t)b * (CC * NP);
        #pragma unroll
        for (int oi = 0; oi < 4; oi++) {
            int c = ot * 64 + o0 + oi - 64;
            int ctg = c >> 5, cq = c & 31;
            ushort4 r;
            r.x = f2bf(acc[0][oi] + bias[oi]);
            r.y = f2bf(acc[1][oi] + bias[oi]);
            r.z = f2bf(acc[2][oi] + bias[oi]);
            r.w = f2bf(acc[3][oi] + bias[oi]);
            size_t idx = ((((size_t)kc * 2 + w2) * 8 + ctg) * 32 + cq) * 16 + hi * 8 + e0;
            *(ushort4*)(vb + idx) = r;
        }
    }
}

// ---------------------------------------------------------------------------
// K3: swapped-operand 32x32 MFMA flash attention, 2D wave split (key x4, ch x2),
// fragment-ordered inputs, REGISTER DOUBLE-BUFFER PREFETCH: all 10 loads of
// chunk k+1 issue before chunk k's compute -> memory latency hidden under the
// QK/softmax/PV phases (R9 showed ~94% stall from load-use serialization).
// launch_bounds(512,2): ~190 regs, 2 waves/SIMD (occupancy beyond 2 proven
// non-binding in R7).
// ---------------------------------------------------------------------------
__global__ __launch_bounds__(512, 2) void flash32_kernel(const unsigned short* __restrict__ qarr,
                                                         const unsigned short* __restrict__ karr,
                                                         const unsigned short* __restrict__ varr,
                                                         float* __restrict__ att) {
    __shared__ float cacc[2][64][68];  // combine: per ch-group, 64 lanes x 64 f32
    __shared__ float cml[2][64][2];    // combine: m, l per lane
    int t    = threadIdx.x;
    int lane = t & 63;
    int w    = t >> 6;                 // 0..7
    int ch   = w & 1;                  // channel half
    int ks   = w >> 1;                 // key quarter
    int j    = blockIdx.x;
    int b    = j & 3;                  // batch -> XCD pinning
    int qt   = j >> 2;                 // 0..127 q-tile (32 rows)

    const unsigned short* qb2 = qarr + (size_t)b * (NP * 32);
    const unsigned short* kb2 = karr + (size_t)b * (NP * 32);
    const unsigned short* vb2 = varr + (size_t)b * (CC * NP);

    int q  = lane & 31;
    int hi = lane >> 5;
    int lq16 = (q * 2 + hi) * 8;       // lane's 16B slot within a 1KB fragment block

    // Q B-frags (held whole kernel): chans f*16 + hi*8 + e of row qt*32+q
    bf16x8 qf0 = *(const bf16x8*)(qb2 + (size_t)(qt * 2 + 0) * 512 + lq16);
    bf16x8 qf1 = *(const bf16x8*)(qb2 + (size_t)(qt * 2 + 1) * 512 + lq16);

    f32x16 acc[4];
    #pragma unroll
    for (int ct = 0; ct < 4; ct++)
        #pragma unroll
        for (int r = 0; r < 16; r++) acc[ct][r] = 0.f;
    float mrun = -3.0e38f, lrun = 0.f;

    const f32x16 z16 = {0.f,0.f,0.f,0.f,0.f,0.f,0.f,0.f,0.f,0.f,0.f,0.f,0.f,0.f,0.f,0.f};

    // ---- prologue: load chunk ks*32 into cur registers
    int kc0 = ks * 32;
    const unsigned short* kcp0 = kb2 + (size_t)kc0 * 1024 + lq16;
    const unsigned short* vcp0 = vb2 + ((size_t)kc0 * 16 + ch * 4) * 512 + lq16;
    bf16x8 kcur0 = *(const bf16x8*)(kcp0);
    bf16x8 kcur1 = *(const bf16x8*)(kcp0 + 512);
    bf16x8 vcur0 = *(const bf16x8*)(vcp0 + 0 * 512);
    bf16x8 vcur1 = *(const bf16x8*)(vcp0 + 1 * 512);
    bf16x8 vcur2 = *(const bf16x8*)(vcp0 + 2 * 512);
    bf16x8 vcur3 = *(const bf16x8*)(vcp0 + 3 * 512);
    bf16x8 vcur4 = *(const bf16x8*)(vcp0 + 8 * 512);
    bf16x8 vcur5 = *(const bf16x8*)(vcp0 + 9 * 512);
    bf16x8 vcur6 = *(const bf16x8*)(vcp0 + 10 * 512);
    bf16x8 vcur7 = *(const bf16x8*)(vcp0 + 11 * 512);

    for (int kci = 0; kci < 32; ++kci) {
        // ---- issue chunk k+1 loads FIRST (in flight during all of chunk k's compute)
        int nid = (kci < 31) ? (kc0 + kci + 1) : (kc0 + kci);   // clamp: last iter reloads
        const unsigned short* kn = kb2 + (size_t)nid * 1024 + lq16;
        const unsigned short* vn = vb2 + ((size_t)nid * 16 + ch * 4) * 512 + lq16;
        bf16x8 knext0 = *(const bf16x8*)(kn);
        bf16x8 knext1 = *(const bf16x8*)(kn + 512);
        bf16x8 vnext0 = *(const bf16x8*)(vn + 0 * 512);
        bf16x8 vnext1 = *(const bf16x8*)(vn + 1 * 512);
        bf16x8 vnext2 = *(const bf16x8*)(vn + 2 * 512);
        bf16x8 vnext3 = *(const bf16x8*)(vn + 3 * 512);
        bf16x8 vnext4 = *(const bf16x8*)(vn + 8 * 512);
        bf16x8 vnext5 = *(const bf16x8*)(vn + 9 * 512);
        bf16x8 vnext6 = *(const bf16x8*)(vn + 10 * 512);
        bf16x8 vnext7 = *(const bf16x8*)(vn + 11 * 512);

        // ---- QK^T swapped: A=K (row=key), B=Q -> S^T (log2 units)
        f32x16 s = __builtin_amdgcn_mfma_f32_32x32x16_bf16(kcur0, qf0, z16, 0, 0, 0);
        s = __builtin_amdgcn_mfma_f32_32x32x16_bf16(kcur1, qf1, s, 0, 0, 0);

        // ---- in-lane max over 16 keys + 1 cross-half swap (permlane, VALU)
        float m01 = fmaxf(s[0], s[1]),   m23 = fmaxf(s[2], s[3]);
        float m45 = fmaxf(s[4], s[5]),   m67 = fmaxf(s[6], s[7]);
        float m89 = fmaxf(s[8], s[9]),   mab = fmaxf(s[10], s[11]);
        float mcd = fmaxf(s[12], s[13]), mef = fmaxf(s[14], s[15]);
        float mx = fmaxf(fmaxf(fmaxf(m01, m23), fmaxf(m45, m67)),
                         fmaxf(fmaxf(m89, mab), fmaxf(mcd, mef)));
        {
            unsigned int mA = __float_as_uint(mx), mB = mA;
            PERMSWAP(mA, mB);
            mx = fmaxf(__uint_as_float(mA), __uint_as_float(mB));
        }

        // ---- defer-max (T13, log2 domain): rescale only when max grew by > ~11.5
        if (!__all(mx - mrun <= 11.5f)) {
            float mn = fmaxf(mrun, mx);
            float sc = exp2fast(mrun - mn);
            mrun = mn;
            lrun *= sc;
            #pragma unroll
            for (int ct = 0; ct < 4; ct++)
                #pragma unroll
                for (int r = 0; r < 16; r++) acc[ct][r] *= sc;
        }

        // ---- P = exp2(S^T - m): pack pairs (bit-exact RNE)
        unsigned int pkr[8];
        float ss = 0.f;
        #pragma unroll
        for (int r2 = 0; r2 < 8; r2++) {
            float p0 = exp2fast(s[2 * r2]     - mrun);
            float p1 = exp2fast(s[2 * r2 + 1] - mrun);
            ss += p0 + p1;
            pkr[r2] = pk2(p0, p1);
        }
        {
            unsigned int sA = __float_as_uint(ss), sB = sA;
            PERMSWAP(sA, sB);
            ss = __uint_as_float(sA) + __uint_as_float(sB);
        }
        lrun += ss;

        // ---- PV with cur V frags: P B-frag via 2 permlane swaps per window
        {
            unsigned int x0 = pkr[0], y0 = pkr[2];
            unsigned int x1 = pkr[1], y1 = pkr[3];
            PERMSWAP(x0, y0);
            PERMSWAP(x1, y1);
            u32x4 fr; fr[0] = x0; fr[1] = x1; fr[2] = y0; fr[3] = y1;
            bf16x8 pf = __builtin_bit_cast(bf16x8, fr);
            acc[0] = __builtin_amdgcn_mfma_f32_32x32x16_bf16(vcur0, pf, acc[0], 0, 0, 0);
            acc[1] = __builtin_amdgcn_mfma_f32_32x32x16_bf16(vcur1, pf, acc[1], 0, 0, 0);
            acc[2] = __builtin_amdgcn_mfma_f32_32x32x16_bf16(vcur2, pf, acc[2], 0, 0, 0);
            acc[3] = __builtin_amdgcn_mfma_f32_32x32x16_bf16(vcur3, pf, acc[3], 0, 0, 0);
        }
        {
            unsigned int x0 = pkr[4], y0 = pkr[6];
            unsigned int x1 = pkr[5], y1 = pkr[7];
            PERMSWAP(x0, y0);
            PERMSWAP(x1, y1);
            u32x4 fr; fr[0] = x0; fr[1] = x1; fr[2] = y0; fr[3] = y1;
            bf16x8 pf = __builtin_bit_cast(bf16x8, fr);
            acc[0] = __builtin_amdgcn_mfma_f32_32x32x16_bf16(vcur4, pf, acc[0], 0, 0, 0);
            acc[1] = __builtin_amdgcn_mfma_f32_32x32x16_bf16(vcur5, pf, acc[1], 0, 0, 0);
            acc[2] = __builtin_amdgcn_mfma_f32_32x32x16_bf16(vcur6, pf, acc[2], 0, 0, 0);
            acc[3] = __builtin_amdgcn_mfma_f32_32x32x16_bf16(vcur7, pf, acc[3], 0, 0, 0);
        }

        // ---- rotate buffers
        kcur0 = knext0; kcur1 = knext1;
        vcur0 = vnext0; vcur1 = vnext1; vcur2 = vnext2; vcur3 = vnext3;
        vcur4 = vnext4; vcur5 = vnext5; vcur6 = vnext6; vcur7 = vnext7;
    }

    // ---- split-K combine within each channel group (ks 3,2,1 -> ks 0)
    for (int sIdx = 3; sIdx >= 1; --sIdx) {
        if (ks == sIdx) {
            #pragma unroll
            for (int ct = 0; ct < 4; ct++)
                #pragma unroll
                for (int rr = 0; rr < 4; rr++) {
                    float4 v4 = {acc[ct][rr*4+0], acc[ct][rr*4+1], acc[ct][rr*4+2], acc[ct][rr*4+3]};
                    *(float4*)&cacc[ch][lane][ct * 16 + rr * 4] = v4;
                }
            cml[ch][lane][0] = mrun; cml[ch][lane][1] = lrun;
        }
        __syncthreads();
        if (ks == 0) {
            float mo = cml[ch][lane][0];
            float lo = cml[ch][lane][1];
            float mn = fmaxf(mrun, mo);
            float e0 = exp2fast(mrun - mn);
            float e1 = exp2fast(mo - mn);
            mrun = mn;
            lrun = lrun * e0 + lo * e1;
            #pragma unroll
            for (int ct = 0; ct < 4; ct++)
                #pragma unroll
                for (int r = 0; r < 16; r++)
                    acc[ct][r] = acc[ct][r] * e0 + cacc[ch][lane][ct * 16 + r] * e1;
        }
        __syncthreads();
    }

    if (ks == 0) {
        float inv = 1.0f / lrun;
        #pragma unroll
        for (int ct = 0; ct < 4; ct++)
            #pragma unroll
            for (int r = 0; r < 16; r++) {
                int c = ch * 128 + ct * 32 + (r & 3) + 8 * (r >> 2) + 4 * hi;
                att[((size_t)b * CC + c) * NP + qt * 32 + q] = acc[ct][r] * inv;
            }
    }
}

// ---------------------------------------------------------------------------
// K4: bilinear x2 upsample (half-pixel, edge clamp) + gamma * up + x, x4 vec
// ---------------------------------------------------------------------------
__global__ __launch_bounds__(256) void upsample_kernel(const float* __restrict__ att,
                                                       const float* __restrict__ x,
                                                       const float* __restrict__ gamma,
                                                       float* __restrict__ out) {
    int tid = blockIdx.x * 256 + threadIdx.x;    // B*C*H*W/4 threads
    int w4 = (tid & 31) * 4;
    int h  = (tid >> 5) & 127;
    int bc = tid >> 12;
    float g = gamma[0];

    float sh = 0.5f * h - 0.25f;
    float fhf = floorf(sh);
    float th = sh - fhf;
    int ih = (int)fhf;
    int ih0 = ih < 0 ? 0 : ih;
    int ih1 = ih + 1 > 63 ? 63 : ih + 1;
    const float* a0r = att + (size_t)bc * NP + ih0 * 64;
    const float* a1r = att + (size_t)bc * NP + ih1 * 64;

    float4 xin = *(const float4*)(x + (size_t)bc * (HH * WW) + h * WW + w4);
    float xv[4] = {xin.x, xin.y, xin.z, xin.w};
    float ov[4];
    #pragma unroll
    for (int k = 0; k < 4; k++) {
        int w = w4 + k;
        float sw = 0.5f * w - 0.25f;
        float fwf = floorf(sw);
        float tw = sw - fwf;
        int iw = (int)fwf;
        int iw0 = iw < 0 ? 0 : iw;
        int iw1 = iw + 1 > 63 ? 63 : iw + 1;
        float v00 = a0r[iw0], v01 = a0r[iw1];
        float v10 = a1r[iw0], v11 = a1r[iw1];
        float top = v00 + tw * (v01 - v00);
        float bot = v10 + tw * (v11 - v10);
        float up  = top + th * (bot - top);
        ov[k] = g * up + xv[k];
    }
    float4 o4 = {ov[0], ov[1], ov[2], ov[3]};
    *(float4*)(out + (size_t)bc * (HH * WW) + h * WW + w4) = o4;
}

// ---------------------------------------------------------------------------
extern "C" void kernel_launch(void* const* d_in, const int* in_sizes, int n_in,
                              void* d_out, int out_size, void* d_ws, size_t ws_size,
                              hipStream_t stream) {
    (void)in_sizes; (void)n_in; (void)out_size; (void)ws_size;
    const float* x     = (const float*)d_in[0];
    const float* wq    = (const float*)d_in[1];
    const float* bq    = (const float*)d_in[2];
    const float* wk    = (const float*)d_in[3];
    const float* bk    = (const float*)d_in[4];
    const float* wv    = (const float*)d_in[5];
    const float* bv    = (const float*)d_in[6];
    const float* gamma = (const float*)d_in[7];
    float* out = (float*)d_out;
    float* ws  = (float*)d_ws;

    float*          xp   = ws;                                 // 4,194,304 f32 (16 MB)
    unsigned short* qarr = (unsigned short*)(ws + 4194304);    // 4*NP*32 = 524,288 bf16 (1 MB)
    unsigned short* karr = qarr + 524288;                      // 524,288 bf16 (1 MB)
    unsigned short* varr = karr + 524288;                      // 4*CC*NP = 4,194,304 bf16 (8 MB)
    float*          att  = (float*)(varr + 4194304);           // 4,194,304 f32 (16 MB)

    pool_kernel<<<16384, 256, 0, stream>>>(x, xp);
    proj_kernel<<<1280, 256, 0, stream>>>(xp, wq, bq, wk, bk, wv, bv, qarr, karr, varr);
    flash32_kernel<<<512, 512, 0, stream>>>(qarr, karr, varr, att);
    upsample_kernel<<<16384, 256, 0, stream>>>(att, x, gamma, out);
}

// Round 11
// 160.782 us; speedup vs baseline: 1.0407x; 1.0407x over previous
//
#include <hip/hip_runtime.h>

// Sizes (fixed by the problem)
#define BB 4
#define CC 256
#define HH 128
#define WW 128
#define HP 64          // pooled H, W
#define NP 4096        // HP*HP tokens per batch

#define L2E 1.4426950408889634f

typedef __attribute__((ext_vector_type(4)))  float f32x4;
typedef __attribute__((ext_vector_type(16))) float f32x16;
typedef __attribute__((ext_vector_type(8)))  short bf16x8;       // 8 bf16 in 4 VGPRs
typedef __attribute__((ext_vector_type(4)))  unsigned int u32x4;

// 2^x via v_exp_f32 (native). NOT __exp2f: that name collides with glibc macros.
static __device__ __forceinline__ float exp2fast(float x) {
    return __builtin_amdgcn_exp2f(x);
}

// float -> bf16 bits, round-to-nearest-even. Reference-matching; R9's __bf16
// cast and R9/R10's PERMSWAP asm both perturbed absmax — reverted to the
// R7-proven shfl_xor + bit-trick path everywhere.
static __device__ __forceinline__ unsigned short f2bf(float f) {
    unsigned int u = __float_as_uint(f);
    u = (u + 0x7FFFu + ((u >> 16) & 1u)) >> 16;
    return (unsigned short)u;
}
static __device__ __forceinline__ unsigned int pk2(float a, float b) {
    return (unsigned int)f2bf(a) | ((unsigned int)f2bf(b) << 16);
}

// ---------------------------------------------------------------------------
// Fragment-ordered workspace layouts (all bf16, per batch):
//   Q2[qtile(128)][f(2)][q(32)][hi(2)][e(8)]
//   K2[kchunk(128)][f(2)][k(32)][hi(2)][e(8)]
//   V2[kc(128)][w2(2)][ctg(8)][q(32)][hi(2)][e(8)]
// A wave's 16B/lane fragment load covers one contiguous 1KB block.
// ---------------------------------------------------------------------------

// ---------------------------------------------------------------------------
// K1: 2x2 average pool. x[b][c][128][128] -> xp[b][c][64*64]
// ---------------------------------------------------------------------------
__global__ __launch_bounds__(256) void pool_kernel(const float* __restrict__ x,
                                                   float* __restrict__ xp) {
    int tid = blockIdx.x * 256 + threadIdx.x;      // B*C*NP threads
    int wp = tid & 63;
    int hp = (tid >> 6) & 63;
    int bc = tid >> 12;
    const float* src = x + (size_t)bc * (HH * WW) + (2 * hp) * WW + 2 * wp;
    float2 a = *(const float2*)(src);
    float2 b = *(const float2*)(src + WW);
    xp[tid] = 0.25f * (a.x + a.y + b.x + b.y);
}

// ---------------------------------------------------------------------------
// K2: fused QKV projection GEMM (fp32 math), bf16 outputs in fragment order.
// Q pre-scaled by log2(e) so flash softmax uses exp2 directly.
// ---------------------------------------------------------------------------
__global__ __launch_bounds__(256) void proj_kernel(const float* __restrict__ xp,
    const float* __restrict__ wq, const float* __restrict__ bq,
    const float* __restrict__ wk, const float* __restrict__ bk,
    const float* __restrict__ wv, const float* __restrict__ bv,
    unsigned short* __restrict__ qarr, unsigned short* __restrict__ karr,
    unsigned short* __restrict__ varr) {
    __shared__ float lx[32][64];    // [c][n]
    __shared__ float lwT[32][64];   // [c][o]
    int t = threadIdx.x;
    int ot = blockIdx.x % 5;
    int nt = (blockIdx.x / 5) & 63;
    int b  = blockIdx.x / 320;

    float acc[4][4];
    #pragma unroll
    for (int i = 0; i < 4; i++)
        #pragma unroll
        for (int j = 0; j < 4; j++) acc[i][j] = 0.f;

    int n0 = (t & 15) * 4;
    int o0 = (t >> 4) * 4;

    int o_l = t >> 2;               // 0..63 weight row
    int og  = ot * 64 + o_l;
    const float* wrow;
    if (og < 32)      wrow = wq + og * CC;
    else if (og < 64) wrow = wk + (og - 32) * CC;
    else              wrow = wv + (og - 64) * CC;
    int c8 = (t & 3) * 8;

    const float* xbase = xp + (size_t)b * CC * NP + nt * 64;
    int cl = t >> 3;                // 0..31
    int nl = (t & 7) * 8;

    for (int c0 = 0; c0 < 256; c0 += 32) {
        const float* xg = xbase + (size_t)(c0 + cl) * NP + nl;
        float4 v0 = *(const float4*)(xg);
        float4 v1 = *(const float4*)(xg + 4);
        float4 w0 = *(const float4*)(wrow + c0 + c8);
        float4 w1 = *(const float4*)(wrow + c0 + c8 + 4);
        __syncthreads();
        *(float4*)&lx[cl][nl]     = v0;
        *(float4*)&lx[cl][nl + 4] = v1;
        lwT[c8 + 0][o_l] = w0.x; lwT[c8 + 1][o_l] = w0.y;
        lwT[c8 + 2][o_l] = w0.z; lwT[c8 + 3][o_l] = w0.w;
        lwT[c8 + 4][o_l] = w1.x; lwT[c8 + 5][o_l] = w1.y;
        lwT[c8 + 6][o_l] = w1.z; lwT[c8 + 7][o_l] = w1.w;
        __syncthreads();
        #pragma unroll
        for (int cc = 0; cc < 32; cc += 4) {
            float4 xv[4], wv4[4];
            #pragma unroll
            for (int ci = 0; ci < 4; ci++) {
                xv[ci]  = *(const float4*)&lx[cc + ci][n0];
                wv4[ci] = *(const float4*)&lwT[cc + ci][o0];
            }
            #pragma unroll
            for (int ci = 0; ci < 4; ci++) {
                float xn[4] = {xv[ci].x, xv[ci].y, xv[ci].z, xv[ci].w};
                float wo[4] = {wv4[ci].x, wv4[ci].y, wv4[ci].z, wv4[ci].w};
                #pragma unroll
                for (int ni = 0; ni < 4; ni++)
                    #pragma unroll
                    for (int oi = 0; oi < 4; oi++)
                        acc[ni][oi] += xn[ni] * wo[oi];
            }
        }
    }

    float bias[4];
    #pragma unroll
    for (int oi = 0; oi < 4; oi++) {
        int o = ot * 64 + o0 + oi;
        bias[oi] = (o < 32) ? bq[o] : (o < 64) ? bk[o - 32] : bv[o - 64];
    }

    if (ot == 0) {
        bool isQ = (o0 < 32);
        int o2 = isQ ? o0 : (o0 - 32);
        int f  = o2 >> 4;
        int hi = (o2 >> 3) & 1;
        int e0 = o2 & 7;
        unsigned short* arr = (isQ ? qarr : karr) + (size_t)b * (NP * 32);
        float qs = isQ ? L2E : 1.0f;   // q pre-scaled for exp2 softmax
        #pragma unroll
        for (int ni = 0; ni < 4; ni++) {
            int n = nt * 64 + n0 + ni;
            ushort4 r;
            r.x = f2bf((acc[ni][0] + bias[0]) * qs);
            r.y = f2bf((acc[ni][1] + bias[1]) * qs);
            r.z = f2bf((acc[ni][2] + bias[2]) * qs);
            r.w = f2bf((acc[ni][3] + bias[3]) * qs);
            size_t idx = (((size_t)(n >> 5) * 2 + f) * 32 + (n & 31)) * 16 + hi * 8 + e0;
            *(ushort4*)(arr + idx) = r;
        }
    } else {
        int n0g = nt * 64 + n0;
        int kc = n0g >> 5, w2 = (n0g >> 4) & 1, hi = (n0g >> 3) & 1, e0 = n0g & 7;
        unsigned short* vb = varr + (size_t)b * (CC * NP);
        #pragma unroll
        for (int oi = 0; oi < 4; oi++) {
            int c = ot * 64 + o0 + oi - 64;
            int ctg = c >> 5, cq = c & 31;
            ushort4 r;
            r.x = f2bf(acc[0][oi] + bias[oi]);
            r.y = f2bf(acc[1][oi] + bias[oi]);
            r.z = f2bf(acc[2][oi] + bias[oi]);
            r.w = f2bf(acc[3][oi] + bias[oi]);
            size_t idx = ((((size_t)kc * 2 + w2) * 8 + ctg) * 32 + cq) * 16 + hi * 8 + e0;
            *(ushort4*)(vb + idx) = r;
        }
    }
}

// ---------------------------------------------------------------------------
// K3: swapped-operand 32x32 MFMA flash attention.
// TWO q-tiles (64 q-rows) per wave: each K/V fragment load feeds 2 q-tiles ->
// flash global load traffic halves vs R7 (V was re-read per 32-row q-tile).
// 512-thread block = 8 waves = ch(2) x ks(4); all waves share the block's
// 64 q-rows. Grid = 256 (1 block/CU). R7-exact numerics (shfl_xor, f2bf).
//
// QK^T (swapped): S^T = mfma_32x32x16(A=K, B=Q).
//   D layout (m74/m101): col=lane&31 = q; row=(r&3)+8*(r>>2)+4*(lane>>5) = key.
// PV: out[c][q] = mfma(A=V^T, B=P); P B-frag built via pk2 + shfl_xor(32).
// ---------------------------------------------------------------------------
__global__ __launch_bounds__(512, 2) void flash32_kernel(const unsigned short* __restrict__ qarr,
                                                         const unsigned short* __restrict__ karr,
                                                         const unsigned short* __restrict__ varr,
                                                         float* __restrict__ att) {
    __shared__ float cacc[2][64][68];  // combine: per ch-group, 64 lanes x 64 f32
    __shared__ float cml[2][64][2];    // combine: m, l per lane
    int t    = threadIdx.x;
    int lane = t & 63;
    int w    = t >> 6;                 // 0..7
    int ch   = w & 1;                  // channel half
    int ks   = w >> 1;                 // key quarter
    int j    = blockIdx.x;
    int b    = j & 3;                  // batch -> XCD pinning (XCDs b and b+4)
    int qt2  = j >> 2;                 // 0..63 q-supertile (64 rows)
    int qt0  = qt2 * 2, qt1 = qt0 + 1;

    const unsigned short* qb2 = qarr + (size_t)b * (NP * 32);
    const unsigned short* kb2 = karr + (size_t)b * (NP * 32);
    const unsigned short* vb2 = varr + (size_t)b * (CC * NP);

    int q  = lane & 31;
    int hi = lane >> 5;
    int lq16 = (q * 2 + hi) * 8;       // lane's 16B slot within a 1KB fragment block

    // Q B-frags for both tiles (held whole kernel)
    bf16x8 qA0 = *(const bf16x8*)(qb2 + (size_t)(qt0 * 2 + 0) * 512 + lq16);
    bf16x8 qA1 = *(const bf16x8*)(qb2 + (size_t)(qt0 * 2 + 1) * 512 + lq16);
    bf16x8 qB0 = *(const bf16x8*)(qb2 + (size_t)(qt1 * 2 + 0) * 512 + lq16);
    bf16x8 qB1 = *(const bf16x8*)(qb2 + (size_t)(qt1 * 2 + 1) * 512 + lq16);

    f32x16 accA[4], accB[4];
    #pragma unroll
    for (int ct = 0; ct < 4; ct++)
        #pragma unroll
        for (int r = 0; r < 16; r++) { accA[ct][r] = 0.f; accB[ct][r] = 0.f; }
    float mrunA = -3.0e38f, lrunA = 0.f;
    float mrunB = -3.0e38f, lrunB = 0.f;

    const f32x16 z16 = {0.f,0.f,0.f,0.f,0.f,0.f,0.f,0.f,0.f,0.f,0.f,0.f,0.f,0.f,0.f,0.f};

    for (int kci = 0; kci < 32; ++kci) {
        int kcidx = ks * 32 + kci;     // key chunk (32 keys)

        // ---- shared K frags; two QK^T (log2 units)
        const unsigned short* kcp = kb2 + (size_t)kcidx * 1024 + lq16;
        bf16x8 kf0 = *(const bf16x8*)(kcp);
        bf16x8 kf1 = *(const bf16x8*)(kcp + 512);
        f32x16 sA = __builtin_amdgcn_mfma_f32_32x32x16_bf16(kf0, qA0, z16, 0, 0, 0);
        sA = __builtin_amdgcn_mfma_f32_32x32x16_bf16(kf1, qA1, sA, 0, 0, 0);
        f32x16 sB = __builtin_amdgcn_mfma_f32_32x32x16_bf16(kf0, qB0, z16, 0, 0, 0);
        sB = __builtin_amdgcn_mfma_f32_32x32x16_bf16(kf1, qB1, sB, 0, 0, 0);

        // ---- softmax tile A
        {
            float m01 = fmaxf(sA[0], sA[1]),   m23 = fmaxf(sA[2], sA[3]);
            float m45 = fmaxf(sA[4], sA[5]),   m67 = fmaxf(sA[6], sA[7]);
            float m89 = fmaxf(sA[8], sA[9]),   mab = fmaxf(sA[10], sA[11]);
            float mcd = fmaxf(sA[12], sA[13]), mef = fmaxf(sA[14], sA[15]);
            float mx = fmaxf(fmaxf(fmaxf(m01, m23), fmaxf(m45, m67)),
                             fmaxf(fmaxf(m89, mab), fmaxf(mcd, mef)));
            mx = fmaxf(mx, __shfl_xor(mx, 32, 64));
            if (!__all(mx - mrunA <= 11.5f)) {
                float mn = fmaxf(mrunA, mx);
                float sc = exp2fast(mrunA - mn);
                mrunA = mn;
                lrunA *= sc;
                #pragma unroll
                for (int ct = 0; ct < 4; ct++)
                    #pragma unroll
                    for (int r = 0; r < 16; r++) accA[ct][r] *= sc;
            }
        }
        unsigned int pkrA[8];
        {
            float ss = 0.f;
            #pragma unroll
            for (int r2 = 0; r2 < 8; r2++) {
                float p0 = exp2fast(sA[2 * r2]     - mrunA);
                float p1 = exp2fast(sA[2 * r2 + 1] - mrunA);
                ss += p0 + p1;
                pkrA[r2] = pk2(p0, p1);
            }
            ss += __shfl_xor(ss, 32, 64);
            lrunA += ss;
        }

        // ---- softmax tile B
        {
            float m01 = fmaxf(sB[0], sB[1]),   m23 = fmaxf(sB[2], sB[3]);
            float m45 = fmaxf(sB[4], sB[5]),   m67 = fmaxf(sB[6], sB[7]);
            float m89 = fmaxf(sB[8], sB[9]),   mab = fmaxf(sB[10], sB[11]);
            float mcd = fmaxf(sB[12], sB[13]), mef = fmaxf(sB[14], sB[15]);
            float mx = fmaxf(fmaxf(fmaxf(m01, m23), fmaxf(m45, m67)),
                             fmaxf(fmaxf(m89, mab), fmaxf(mcd, mef)));
            mx = fmaxf(mx, __shfl_xor(mx, 32, 64));
            if (!__all(mx - mrunB <= 11.5f)) {
                float mn = fmaxf(mrunB, mx);
                float sc = exp2fast(mrunB - mn);
                mrunB = mn;
                lrunB *= sc;
                #pragma unroll
                for (int ct = 0; ct < 4; ct++)
                    #pragma unroll
                    for (int r = 0; r < 16; r++) accB[ct][r] *= sc;
            }
        }
        unsigned int pkrB[8];
        {
            float ss = 0.f;
            #pragma unroll
            for (int r2 = 0; r2 < 8; r2++) {
                float p0 = exp2fast(sB[2 * r2]     - mrunB);
                float p1 = exp2fast(sB[2 * r2 + 1] - mrunB);
                ss += p0 + p1;
                pkrB[r2] = pk2(p0, p1);
            }
            ss += __shfl_xor(ss, 32, 64);
            lrunB += ss;
        }

        // ---- PV: per 16-key window, shared V frags feed both tiles
        const unsigned short* vcp = vb2 + ((size_t)kcidx * 16 + ch * 4) * 512 + lq16;
        #pragma unroll
        for (int w2 = 0; w2 < 2; w2++) {
            bf16x8 vf0 = *(const bf16x8*)(vcp + (size_t)(w2 * 8 + 0) * 512);
            bf16x8 vf1 = *(const bf16x8*)(vcp + (size_t)(w2 * 8 + 1) * 512);
            bf16x8 vf2 = *(const bf16x8*)(vcp + (size_t)(w2 * 8 + 2) * 512);
            bf16x8 vf3 = *(const bf16x8*)(vcp + (size_t)(w2 * 8 + 3) * 512);

            unsigned int aA0 = pkrA[4 * w2 + 0], aA1 = pkrA[4 * w2 + 1];
            unsigned int cA0 = pkrA[4 * w2 + 2], cA1 = pkrA[4 * w2 + 3];
            unsigned int saA0 = __shfl_xor(aA0, 32, 64), saA1 = __shfl_xor(aA1, 32, 64);
            unsigned int scA0 = __shfl_xor(cA0, 32, 64), scA1 = __shfl_xor(cA1, 32, 64);
            u32x4 frA;
            if (hi == 0) { frA[0] = aA0;  frA[1] = aA1;  frA[2] = saA0; frA[3] = saA1; }
            else         { frA[0] = scA0; frA[1] = scA1; frA[2] = cA0;  frA[3] = cA1;  }
            bf16x8 pfA = __builtin_bit_cast(bf16x8, frA);

            unsigned int aB0 = pkrB[4 * w2 + 0], aB1 = pkrB[4 * w2 + 1];
            unsigned int cB0 = pkrB[4 * w2 + 2], cB1 = pkrB[4 * w2 + 3];
            unsigned int saB0 = __shfl_xor(aB0, 32, 64), saB1 = __shfl_xor(aB1, 32, 64);
            unsigned int scB0 = __shfl_xor(cB0, 32, 64), scB1 = __shfl_xor(cB1, 32, 64);
            u32x4 frB;
            if (hi == 0) { frB[0] = aB0;  frB[1] = aB1;  frB[2] = saB0; frB[3] = saB1; }
            else         { frB[0] = scB0; frB[1] = scB1; frB[2] = cB0;  frB[3] = cB1;  }
            bf16x8 pfB = __builtin_bit_cast(bf16x8, frB);

            accA[0] = __builtin_amdgcn_mfma_f32_32x32x16_bf16(vf0, pfA, accA[0], 0, 0, 0);
            accB[0] = __builtin_amdgcn_mfma_f32_32x32x16_bf16(vf0, pfB, accB[0], 0, 0, 0);
            accA[1] = __builtin_amdgcn_mfma_f32_32x32x16_bf16(vf1, pfA, accA[1], 0, 0, 0);
            accB[1] = __builtin_amdgcn_mfma_f32_32x32x16_bf16(vf1, pfB, accB[1], 0, 0, 0);
            accA[2] = __builtin_amdgcn_mfma_f32_32x32x16_bf16(vf2, pfA, accA[2], 0, 0, 0);
            accB[2] = __builtin_amdgcn_mfma_f32_32x32x16_bf16(vf2, pfB, accB[2], 0, 0, 0);
            accA[3] = __builtin_amdgcn_mfma_f32_32x32x16_bf16(vf3, pfA, accA[3], 0, 0, 0);
            accB[3] = __builtin_amdgcn_mfma_f32_32x32x16_bf16(vf3, pfB, accB[3], 0, 0, 0);
        }
    }

    // ---- split-K combine (ks 3,2,1 -> ks 0), tile A then tile B (6 rounds,
    //      keeps LDS at 37 KB)
    #pragma unroll
    for (int tile = 0; tile < 2; tile++) {
        for (int sIdx = 3; sIdx >= 1; --sIdx) {
            if (ks == sIdx) {
                #pragma unroll
                for (int ct = 0; ct < 4; ct++)
                    #pragma unroll
                    for (int rr = 0; rr < 4; rr++) {
                        float4 v4;
                        if (tile == 0)
                            v4 = (float4){accA[ct][rr*4+0], accA[ct][rr*4+1], accA[ct][rr*4+2], accA[ct][rr*4+3]};
                        else
                            v4 = (float4){accB[ct][rr*4+0], accB[ct][rr*4+1], accB[ct][rr*4+2], accB[ct][rr*4+3]};
                        *(float4*)&cacc[ch][lane][ct * 16 + rr * 4] = v4;
                    }
                cml[ch][lane][0] = (tile == 0) ? mrunA : mrunB;
                cml[ch][lane][1] = (tile == 0) ? lrunA : lrunB;
            }
            __syncthreads();
            if (ks == 0) {
                float mo = cml[ch][lane][0];
                float lo = cml[ch][lane][1];
                float mr = (tile == 0) ? mrunA : mrunB;
                float lr = (tile == 0) ? lrunA : lrunB;
                float mn = fmaxf(mr, mo);
                float e0 = exp2fast(mr - mn);
                float e1 = exp2fast(mo - mn);
                if (tile == 0) { mrunA = mn; lrunA = lrunA * e0 + lo * e1; }
                else           { mrunB = mn; lrunB = lrunB * e0 + lo * e1; }
                #pragma unroll
                for (int ct = 0; ct < 4; ct++)
                    #pragma unroll
                    for (int r = 0; r < 16; r++) {
                        if (tile == 0)
                            accA[ct][r] = accA[ct][r] * e0 + cacc[ch][lane][ct * 16 + r] * e1;
                        else
                            accB[ct][r] = accB[ct][r] * e0 + cacc[ch][lane][ct * 16 + r] * e1;
                    }
            }
            __syncthreads();
        }
    }

    if (ks == 0) {
        float invA = 1.0f / lrunA;
        float invB = 1.0f / lrunB;
        #pragma unroll
        for (int ct = 0; ct < 4; ct++)
            #pragma unroll
            for (int r = 0; r < 16; r++) {
                int c = ch * 128 + ct * 32 + (r & 3) + 8 * (r >> 2) + 4 * hi;
                float* ob = att + ((size_t)b * CC + c) * NP;
                ob[qt0 * 32 + q] = accA[ct][r] * invA;
                ob[qt1 * 32 + q] = accB[ct][r] * invB;
            }
    }
}

// ---------------------------------------------------------------------------
// K4: bilinear x2 upsample (half-pixel, edge clamp) + gamma * up + x, x4 vec
// ---------------------------------------------------------------------------
__global__ __launch_bounds__(256) void upsample_kernel(const float* __restrict__ att,
                                                       const float* __restrict__ x,
                                                       const float* __restrict__ gamma,
                                                       float* __restrict__ out) {
    int tid = blockIdx.x * 256 + threadIdx.x;    // B*C*H*W/4 threads
    int w4 = (tid & 31) * 4;
    int h  = (tid >> 5) & 127;
    int bc = tid >> 12;
    float g = gamma[0];

    float sh = 0.5f * h - 0.25f;
    float fhf = floorf(sh);
    float th = sh - fhf;
    int ih = (int)fhf;
    int ih0 = ih < 0 ? 0 : ih;
    int ih1 = ih + 1 > 63 ? 63 : ih + 1;
    const float* a0r = att + (size_t)bc * NP + ih0 * 64;
    const float* a1r = att + (size_t)bc * NP + ih1 * 64;

    float4 xin = *(const float4*)(x + (size_t)bc * (HH * WW) + h * WW + w4);
    float xv[4] = {xin.x, xin.y, xin.z, xin.w};
    float ov[4];
    #pragma unroll
    for (int k = 0; k < 4; k++) {
        int w = w4 + k;
        float sw = 0.5f * w - 0.25f;
        float fwf = floorf(sw);
        float tw = sw - fwf;
        int iw = (int)fwf;
        int iw0 = iw < 0 ? 0 : iw;
        int iw1 = iw + 1 > 63 ? 63 : iw + 1;
        float v00 = a0r[iw0], v01 = a0r[iw1];
        float v10 = a1r[iw0], v11 = a1r[iw1];
        float top = v00 + tw * (v01 - v00);
        float bot = v10 + tw * (v11 - v10);
        float up  = top + th * (bot - top);
        ov[k] = g * up + xv[k];
    }
    float4 o4 = {ov[0], ov[1], ov[2], ov[3]};
    *(float4*)(out + (size_t)bc * (HH * WW) + h * WW + w4) = o4;
}

// ---------------------------------------------------------------------------
extern "C" void kernel_launch(void* const* d_in, const int* in_sizes, int n_in,
                              void* d_out, int out_size, void* d_ws, size_t ws_size,
                              hipStream_t stream) {
    (void)in_sizes; (void)n_in; (void)out_size; (void)ws_size;
    const float* x     = (const float*)d_in[0];
    const float* wq    = (const float*)d_in[1];
    const float* bq    = (const float*)d_in[2];
    const float* wk    = (const float*)d_in[3];
    const float* bk    = (const float*)d_in[4];
    const float* wv    = (const float*)d_in[5];
    const float* bv    = (const float*)d_in[6];
    const float* gamma = (const float*)d_in[7];
    float* out = (float*)d_out;
    float* ws  = (float*)d_ws;

    float*          xp   = ws;                                 // 4,194,304 f32 (16 MB)
    unsigned short* qarr = (unsigned short*)(ws + 4194304);    // 4*NP*32 = 524,288 bf16 (1 MB)
    unsigned short* karr = qarr + 524288;                      // 524,288 bf16 (1 MB)
    unsigned short* varr = karr + 524288;                      // 4*CC*NP = 4,194,304 bf16 (8 MB)
    float*          att  = (float*)(varr + 4194304);           // 4,194,304 f32 (16 MB)

    pool_kernel<<<16384, 256, 0, stream>>>(x, xp);
    proj_kernel<<<1280, 256, 0, stream>>>(xp, wq, bq, wk, bk, wv, bv, qarr, karr, varr);
    flash32_kernel<<<256, 512, 0, stream>>>(qarr, karr, varr, att);
    upsample_kernel<<<16384, 256, 0, stream>>>(att, x, gamma, out);
}

// Round 12
// 159.906 us; speedup vs baseline: 1.0464x; 1.0055x over previous
//
#include <hip/hip_runtime.h>

// Sizes (fixed by the problem)
#define BB 4
#define CC 256
#define HH 128
#define WW 128
#define HP 64          // pooled H, W
#define NP 4096        // HP*HP tokens per batch

#define L2E 1.4426950408889634f

typedef __attribute__((ext_vector_type(4)))  float f32x4;
typedef __attribute__((ext_vector_type(16))) float f32x16;
typedef __attribute__((ext_vector_type(8)))  short bf16x8;       // 8 bf16 in 4 VGPRs
typedef __attribute__((ext_vector_type(4)))  unsigned int u32x4;

// 2^x via v_exp_f32 (native). NOT __exp2f: that name collides with glibc macros.
static __device__ __forceinline__ float exp2fast(float x) {
    return __builtin_amdgcn_exp2f(x);
}

// float -> bf16 bits, round-to-nearest-even. Reference-matching. (R9's __bf16
// cast and R9/R10's PERMSWAP inline-asm both perturbed absmax — stay on the
// shfl_xor + bit-trick path.)
static __device__ __forceinline__ unsigned short f2bf(float f) {
    unsigned int u = __float_as_uint(f);
    u = (u + 0x7FFFu + ((u >> 16) & 1u)) >> 16;
    return (unsigned short)u;
}
static __device__ __forceinline__ unsigned int pk2(float a, float b) {
    return (unsigned int)f2bf(a) | ((unsigned int)f2bf(b) << 16);
}

// ---------------------------------------------------------------------------
// Fragment-ordered workspace layouts (all bf16, per batch):
//   Q2[qtile(128)][f(2)][q(32)][hi(2)][e(8)]
//   K2[kchunk(128)][f(2)][k(32)][hi(2)][e(8)]
//   V2[kc(128)][w2(2)][ctg(8)][q(32)][hi(2)][e(8)]
// A wave's 16B/lane fragment load covers one contiguous 1KB block.
// ---------------------------------------------------------------------------

// ---------------------------------------------------------------------------
// K1: 2x2 average pool. x[b][c][128][128] -> xp[b][c][64*64]
// ---------------------------------------------------------------------------
__global__ __launch_bounds__(256) void pool_kernel(const float* __restrict__ x,
                                                   float* __restrict__ xp) {
    int tid = blockIdx.x * 256 + threadIdx.x;      // B*C*NP threads
    int wp = tid & 63;
    int hp = (tid >> 6) & 63;
    int bc = tid >> 12;
    const float* src = x + (size_t)bc * (HH * WW) + (2 * hp) * WW + 2 * wp;
    float2 a = *(const float2*)(src);
    float2 b = *(const float2*)(src + WW);
    xp[tid] = 0.25f * (a.x + a.y + b.x + b.y);
}

// ---------------------------------------------------------------------------
// K2: fused QKV projection GEMM (fp32 math), bf16 outputs in fragment order.
// Q pre-scaled by log2(e) so flash softmax uses exp2 directly.
// ---------------------------------------------------------------------------
__global__ __launch_bounds__(256) void proj_kernel(const float* __restrict__ xp,
    const float* __restrict__ wq, const float* __restrict__ bq,
    const float* __restrict__ wk, const float* __restrict__ bk,
    const float* __restrict__ wv, const float* __restrict__ bv,
    unsigned short* __restrict__ qarr, unsigned short* __restrict__ karr,
    unsigned short* __restrict__ varr) {
    __shared__ float lx[32][64];    // [c][n]
    __shared__ float lwT[32][64];   // [c][o]
    int t = threadIdx.x;
    int ot = blockIdx.x % 5;
    int nt = (blockIdx.x / 5) & 63;
    int b  = blockIdx.x / 320;

    float acc[4][4];
    #pragma unroll
    for (int i = 0; i < 4; i++)
        #pragma unroll
        for (int j = 0; j < 4; j++) acc[i][j] = 0.f;

    int n0 = (t & 15) * 4;
    int o0 = (t >> 4) * 4;

    int o_l = t >> 2;               // 0..63 weight row
    int og  = ot * 64 + o_l;
    const float* wrow;
    if (og < 32)      wrow = wq + og * CC;
    else if (og < 64) wrow = wk + (og - 32) * CC;
    else              wrow = wv + (og - 64) * CC;
    int c8 = (t & 3) * 8;

    const float* xbase = xp + (size_t)b * CC * NP + nt * 64;
    int cl = t >> 3;                // 0..31
    int nl = (t & 7) * 8;

    for (int c0 = 0; c0 < 256; c0 += 32) {
        const float* xg = xbase + (size_t)(c0 + cl) * NP + nl;
        float4 v0 = *(const float4*)(xg);
        float4 v1 = *(const float4*)(xg + 4);
        float4 w0 = *(const float4*)(wrow + c0 + c8);
        float4 w1 = *(const float4*)(wrow + c0 + c8 + 4);
        __syncthreads();
        *(float4*)&lx[cl][nl]     = v0;
        *(float4*)&lx[cl][nl + 4] = v1;
        lwT[c8 + 0][o_l] = w0.x; lwT[c8 + 1][o_l] = w0.y;
        lwT[c8 + 2][o_l] = w0.z; lwT[c8 + 3][o_l] = w0.w;
        lwT[c8 + 4][o_l] = w1.x; lwT[c8 + 5][o_l] = w1.y;
        lwT[c8 + 6][o_l] = w1.z; lwT[c8 + 7][o_l] = w1.w;
        __syncthreads();
        #pragma unroll
        for (int cc = 0; cc < 32; cc += 4) {
            float4 xv[4], wv4[4];
            #pragma unroll
            for (int ci = 0; ci < 4; ci++) {
                xv[ci]  = *(const float4*)&lx[cc + ci][n0];
                wv4[ci] = *(const float4*)&lwT[cc + ci][o0];
            }
            #pragma unroll
            for (int ci = 0; ci < 4; ci++) {
                float xn[4] = {xv[ci].x, xv[ci].y, xv[ci].z, xv[ci].w};
                float wo[4] = {wv4[ci].x, wv4[ci].y, wv4[ci].z, wv4[ci].w};
                #pragma unroll
                for (int ni = 0; ni < 4; ni++)
                    #pragma unroll
                    for (int oi = 0; oi < 4; oi++)
                        acc[ni][oi] += xn[ni] * wo[oi];
            }
        }
    }

    float bias[4];
    #pragma unroll
    for (int oi = 0; oi < 4; oi++) {
        int o = ot * 64 + o0 + oi;
        bias[oi] = (o < 32) ? bq[o] : (o < 64) ? bk[o - 32] : bv[o - 64];
    }

    if (ot == 0) {
        bool isQ = (o0 < 32);
        int o2 = isQ ? o0 : (o0 - 32);
        int f  = o2 >> 4;
        int hi = (o2 >> 3) & 1;
        int e0 = o2 & 7;
        unsigned short* arr = (isQ ? qarr : karr) + (size_t)b * (NP * 32);
        float qs = isQ ? L2E : 1.0f;   // q pre-scaled for exp2 softmax
        #pragma unroll
        for (int ni = 0; ni < 4; ni++) {
            int n = nt * 64 + n0 + ni;
            ushort4 r;
            r.x = f2bf((acc[ni][0] + bias[0]) * qs);
            r.y = f2bf((acc[ni][1] + bias[1]) * qs);
            r.z = f2bf((acc[ni][2] + bias[2]) * qs);
            r.w = f2bf((acc[ni][3] + bias[3]) * qs);
            size_t idx = (((size_t)(n >> 5) * 2 + f) * 32 + (n & 31)) * 16 + hi * 8 + e0;
            *(ushort4*)(arr + idx) = r;
        }
    } else {
        int n0g = nt * 64 + n0;
        int kc = n0g >> 5, w2 = (n0g >> 4) & 1, hi = (n0g >> 3) & 1, e0 = n0g & 7;
        unsigned short* vb = varr + (size_t)b * (CC * NP);
        #pragma unroll
        for (int oi = 0; oi < 4; oi++) {
            int c = ot * 64 + o0 + oi - 64;
            int ctg = c >> 5, cq = c & 31;
            ushort4 r;
            r.x = f2bf(acc[0][oi] + bias[oi]);
            r.y = f2bf(acc[1][oi] + bias[oi]);
            r.z = f2bf(acc[2][oi] + bias[oi]);
            r.w = f2bf(acc[3][oi] + bias[oi]);
            size_t idx = ((((size_t)kc * 2 + w2) * 8 + ctg) * 32 + cq) * 16 + hi * 8 + e0;
            *(ushort4*)(vb + idx) = r;
        }
    }
}

// ---------------------------------------------------------------------------
// K3: swapped-operand 32x32 MFMA flash attention, FULL-CHANNEL waves.
// One wave = one 32-row q-tile x ALL 256 channels (acc = 8 x f32x16 = 128
// regs; R5 precedent: fits at 2 waves/SIMD, no spill). Softmax + P-frag build
// computed ONCE per output unit (was twice in the ch-split design — that
// duplication was the binding 47%-VALU term, R11 post-mortem).
// Block = 4 waves (ks split over 1024-key ranges); grid 512 = 2 blocks/CU.
// Fragment-ordered inputs; R7-exact numerics (shfl_xor, f2bf).
//
// QK^T (swapped): S^T = mfma_32x32x16(A=K, B=Q).
//   D layout (m74/m101): col=lane&31 = q; row=(r&3)+8*(r>>2)+4*(lane>>5) = key.
// PV: out[c][q] = mfma(A=V^T, B=P); P B-frag built via pk2 + shfl_xor(32).
// ---------------------------------------------------------------------------
__global__ __launch_bounds__(256, 2) void flash32_kernel(const unsigned short* __restrict__ qarr,
                                                         const unsigned short* __restrict__ karr,
                                                         const unsigned short* __restrict__ varr,
                                                         float* __restrict__ att) {
    __shared__ float cacc[64][136];    // combine: one wave's 128 acc f32 per lane
    __shared__ float cml[64][2];       // combine: m, l per lane
    int t    = threadIdx.x;
    int lane = t & 63;
    int ks   = t >> 6;                 // 0..3 key quarter
    int j    = blockIdx.x;
    int b    = j & 3;                  // batch -> XCD pinning (XCDs b, b+4)
    int qt   = j >> 2;                 // 0..127 q-tile (32 rows)

    const unsigned short* qb2 = qarr + (size_t)b * (NP * 32);
    const unsigned short* kb2 = karr + (size_t)b * (NP * 32);
    const unsigned short* vb2 = varr + (size_t)b * (CC * NP);

    int q  = lane & 31;
    int hi = lane >> 5;
    int lq16 = (q * 2 + hi) * 8;       // lane's 16B slot within a 1KB fragment block

    // Q B-frags (held whole kernel)
    bf16x8 qf0 = *(const bf16x8*)(qb2 + (size_t)(qt * 2 + 0) * 512 + lq16);
    bf16x8 qf1 = *(const bf16x8*)(qb2 + (size_t)(qt * 2 + 1) * 512 + lq16);

    f32x16 acc[8];
    #pragma unroll
    for (int ct = 0; ct < 8; ct++)
        #pragma unroll
        for (int r = 0; r < 16; r++) acc[ct][r] = 0.f;
    float mrun = -3.0e38f, lrun = 0.f;

    const f32x16 z16 = {0.f,0.f,0.f,0.f,0.f,0.f,0.f,0.f,0.f,0.f,0.f,0.f,0.f,0.f,0.f,0.f};

    for (int kci = 0; kci < 32; ++kci) {
        int kcidx = ks * 32 + kci;     // key chunk (32 keys)

        // ---- QK^T swapped: A=K (row=key), B=Q -> S^T (log2 units)
        const unsigned short* kcp = kb2 + (size_t)kcidx * 1024 + lq16;
        bf16x8 kf0 = *(const bf16x8*)(kcp);
        bf16x8 kf1 = *(const bf16x8*)(kcp + 512);
        f32x16 s = __builtin_amdgcn_mfma_f32_32x32x16_bf16(kf0, qf0, z16, 0, 0, 0);
        s = __builtin_amdgcn_mfma_f32_32x32x16_bf16(kf1, qf1, s, 0, 0, 0);

        // ---- in-lane max over 16 keys + 1 cross-half swap
        float m01 = fmaxf(s[0], s[1]),   m23 = fmaxf(s[2], s[3]);
        float m45 = fmaxf(s[4], s[5]),   m67 = fmaxf(s[6], s[7]);
        float m89 = fmaxf(s[8], s[9]),   mab = fmaxf(s[10], s[11]);
        float mcd = fmaxf(s[12], s[13]), mef = fmaxf(s[14], s[15]);
        float mx = fmaxf(fmaxf(fmaxf(m01, m23), fmaxf(m45, m67)),
                         fmaxf(fmaxf(m89, mab), fmaxf(mcd, mef)));
        mx = fmaxf(mx, __shfl_xor(mx, 32, 64));

        // ---- defer-max (T13, log2 domain): rescale only when max grew by > ~11.5
        if (!__all(mx - mrun <= 11.5f)) {
            float mn = fmaxf(mrun, mx);
            float sc = exp2fast(mrun - mn);
            mrun = mn;
            lrun *= sc;
            #pragma unroll
            for (int ct = 0; ct < 8; ct++)
                #pragma unroll
                for (int r = 0; r < 16; r++) acc[ct][r] *= sc;
        }

        // ---- P = exp2(S^T - m): pack pairs (bit-exact RNE)
        unsigned int pkr[8];
        float ss = 0.f;
        #pragma unroll
        for (int r2 = 0; r2 < 8; r2++) {
            float p0 = exp2fast(s[2 * r2]     - mrun);
            float p1 = exp2fast(s[2 * r2 + 1] - mrun);
            ss += p0 + p1;
            pkr[r2] = pk2(p0, p1);
        }
        ss += __shfl_xor(ss, 32, 64);
        lrun += ss;

        // ---- PV: per 16-key window, ONE P B-frag feeds 8 channel tiles
        #pragma unroll
        for (int w2 = 0; w2 < 2; w2++) {
            unsigned int a0 = pkr[4 * w2 + 0], a1 = pkr[4 * w2 + 1];
            unsigned int c0 = pkr[4 * w2 + 2], c1 = pkr[4 * w2 + 3];
            unsigned int sa0 = __shfl_xor(a0, 32, 64), sa1 = __shfl_xor(a1, 32, 64);
            unsigned int sc0 = __shfl_xor(c0, 32, 64), sc1 = __shfl_xor(c1, 32, 64);
            u32x4 fr;
            if (hi == 0) { fr[0] = a0;  fr[1] = a1;  fr[2] = sa0; fr[3] = sa1; }
            else         { fr[0] = sc0; fr[1] = sc1; fr[2] = c0;  fr[3] = c1;  }
            bf16x8 pf = __builtin_bit_cast(bf16x8, fr);
            const unsigned short* vcp = vb2 + ((size_t)kcidx * 16 + w2 * 8) * 512 + lq16;
            #pragma unroll
            for (int ct = 0; ct < 8; ct++) {
                bf16x8 vf = *(const bf16x8*)(vcp + (size_t)ct * 512);
                acc[ct] = __builtin_amdgcn_mfma_f32_32x32x16_bf16(vf, pf, acc[ct], 0, 0, 0);
            }
        }
    }

    // ---- split-K combine: ks 3,2,1 hand state to ks 0 (elementwise per lane)
    for (int sIdx = 3; sIdx >= 1; --sIdx) {
        if (ks == sIdx) {
            #pragma unroll
            for (int ct = 0; ct < 8; ct++)
                #pragma unroll
                for (int rr = 0; rr < 4; rr++) {
                    float4 v4 = {acc[ct][rr*4+0], acc[ct][rr*4+1], acc[ct][rr*4+2], acc[ct][rr*4+3]};
                    *(float4*)&cacc[lane][ct * 16 + rr * 4] = v4;
                }
            cml[lane][0] = mrun; cml[lane][1] = lrun;
        }
        __syncthreads();
        if (ks == 0) {
            float mo = cml[lane][0];
            float lo = cml[lane][1];
            float mn = fmaxf(mrun, mo);
            float e0 = exp2fast(mrun - mn);
            float e1 = exp2fast(mo - mn);
            mrun = mn;
            lrun = lrun * e0 + lo * e1;
            #pragma unroll
            for (int ct = 0; ct < 8; ct++)
                #pragma unroll
                for (int r = 0; r < 16; r++)
                    acc[ct][r] = acc[ct][r] * e0 + cacc[lane][ct * 16 + r] * e1;
        }
        __syncthreads();
    }

    if (ks == 0) {
        float inv = 1.0f / lrun;
        #pragma unroll
        for (int ct = 0; ct < 8; ct++)
            #pragma unroll
            for (int r = 0; r < 16; r++) {
                int c = ct * 32 + (r & 3) + 8 * (r >> 2) + 4 * hi;
                att[((size_t)b * CC + c) * NP + qt * 32 + q] = acc[ct][r] * inv;
            }
    }
}

// ---------------------------------------------------------------------------
// K4: bilinear x2 upsample (half-pixel, edge clamp) + gamma * up + x, x4 vec
// ---------------------------------------------------------------------------
__global__ __launch_bounds__(256) void upsample_kernel(const float* __restrict__ att,
                                                       const float* __restrict__ x,
                                                       const float* __restrict__ gamma,
                                                       float* __restrict__ out) {
    int tid = blockIdx.x * 256 + threadIdx.x;    // B*C*H*W/4 threads
    int w4 = (tid & 31) * 4;
    int h  = (tid >> 5) & 127;
    int bc = tid >> 12;
    float g = gamma[0];

    float sh = 0.5f * h - 0.25f;
    float fhf = floorf(sh);
    float th = sh - fhf;
    int ih = (int)fhf;
    int ih0 = ih < 0 ? 0 : ih;
    int ih1 = ih + 1 > 63 ? 63 : ih + 1;
    const float* a0r = att + (size_t)bc * NP + ih0 * 64;
    const float* a1r = att + (size_t)bc * NP + ih1 * 64;

    float4 xin = *(const float4*)(x + (size_t)bc * (HH * WW) + h * WW + w4);
    float xv[4] = {xin.x, xin.y, xin.z, xin.w};
    float ov[4];
    #pragma unroll
    for (int k = 0; k < 4; k++) {
        int w = w4 + k;
        float sw = 0.5f * w - 0.25f;
        float fwf = floorf(sw);
        float tw = sw - fwf;
        int iw = (int)fwf;
        int iw0 = iw < 0 ? 0 : iw;
        int iw1 = iw + 1 > 63 ? 63 : iw + 1;
        float v00 = a0r[iw0], v01 = a0r[iw1];
        float v10 = a1r[iw0], v11 = a1r[iw1];
        float top = v00 + tw * (v01 - v00);
        float bot = v10 + tw * (v11 - v10);
        float up  = top + th * (bot - top);
        ov[k] = g * up + xv[k];
    }
    float4 o4 = {ov[0], ov[1], ov[2], ov[3]};
    *(float4*)(out + (size_t)bc * (HH * WW) + h * WW + w4) = o4;
}

// ---------------------------------------------------------------------------
extern "C" void kernel_launch(void* const* d_in, const int* in_sizes, int n_in,
                              void* d_out, int out_size, void* d_ws, size_t ws_size,
                              hipStream_t stream) {
    (void)in_sizes; (void)n_in; (void)out_size; (void)ws_size;
    const float* x     = (const float*)d_in[0];
    const float* wq    = (const float*)d_in[1];
    const float* bq    = (const float*)d_in[2];
    const float* wk    = (const float*)d_in[3];
    const float* bk    = (const float*)d_in[4];
    const float* wv    = (const float*)d_in[5];
    const float* bv    = (const float*)d_in[6];
    const float* gamma = (const float*)d_in[7];
    float* out = (float*)d_out;
    float* ws  = (float*)d_ws;

    float*          xp   = ws;                                 // 4,194,304 f32 (16 MB)
    unsigned short* qarr = (unsigned short*)(ws + 4194304);    // 4*NP*32 = 524,288 bf16 (1 MB)
    unsigned short* karr = qarr + 524288;                      // 524,288 bf16 (1 MB)
    unsigned short* varr = karr + 524288;                      // 4*CC*NP = 4,194,304 bf16 (8 MB)
    float*          att  = (float*)(varr + 4194304);           // 4,194,304 f32 (16 MB)

    pool_kernel<<<16384, 256, 0, stream>>>(x, xp);
    proj_kernel<<<1280, 256, 0, stream>>>(xp, wq, bq, wk, bk, wv, bv, qarr, karr, varr);
    flash32_kernel<<<512, 256, 0, stream>>>(qarr, karr, varr, att);
    upsample_kernel<<<16384, 256, 0, stream>>>(att, x, gamma, out);
}

// Round 13
// 132.965 us; speedup vs baseline: 1.2585x; 1.2026x over previous
//
#include <hip/hip_runtime.h>

// Sizes (fixed by the problem)
#define BB 4
#define CC 256
#define HH 128
#define WW 128
#define HP 64          // pooled H, W
#define NP 4096        // HP*HP tokens per batch

#define L2E 1.4426950408889634f

typedef __attribute__((ext_vector_type(4)))  float f32x4;
typedef __attribute__((ext_vector_type(16))) float f32x16;
typedef __attribute__((ext_vector_type(8)))  short bf16x8;       // 8 bf16 in 4 VGPRs
typedef __attribute__((ext_vector_type(4)))  unsigned int u32x4;

// 2^x via v_exp_f32 (native). NOT __exp2f: that name collides with glibc macros.
static __device__ __forceinline__ float exp2fast(float x) {
    return __builtin_amdgcn_exp2f(x);
}

// float -> bf16 bits, round-to-nearest-even. Reference-matching. (R9's __bf16
// cast and R9/R10's PERMSWAP inline-asm both perturbed absmax — stay on the
// shfl_xor + bit-trick path.)
static __device__ __forceinline__ unsigned short f2bf(float f) {
    unsigned int u = __float_as_uint(f);
    u = (u + 0x7FFFu + ((u >> 16) & 1u)) >> 16;
    return (unsigned short)u;
}
static __device__ __forceinline__ unsigned int pk2(float a, float b) {
    return (unsigned int)f2bf(a) | ((unsigned int)f2bf(b) << 16);
}

// ---------------------------------------------------------------------------
// Fragment-ordered layouts (bf16):
//   xfrag[b][nt(128)][ks(16)][lane(64)][e(8)] : B-frag, X[c][n]:
//       n = nt*32 + (lane&31), c = ks*16 + (lane>>5)*8 + e
//   wfrag[ot(10)][ks(16)][lane(64)][e(8)]     : A-frag, W[o][c]:
//       o = ot*32 + (lane&31), c = ks*16 + (lane>>5)*8 + e  (Q rows xL2E)
//   Q2[qtile(128)][f(2)][q(32)][hi(2)][e(8)]  : flash Q (pre-scaled)
//   K2[kchunk(128)][f(2)][k(32)][hi(2)][e(8)]
//   V2[kc(128)][w2(2)][ctg(8)][q(32)][hi(2)][e(8)]
// mfma_32x32x16_bf16 (m74/m101): A row=lane&31, k=(lane>>5)*8+e; B col=lane&31,
// same k; D col=lane&31, row=(r&3)+8*(r>>2)+4*(lane>>5).
// ---------------------------------------------------------------------------

// ---------------------------------------------------------------------------
// K1: fused 2x2 avg-pool + bf16 B-fragment layout. One thread = one 16B slot.
// ---------------------------------------------------------------------------
__global__ __launch_bounds__(256) void pool2_kernel(const float* __restrict__ x,
                                                    unsigned short* __restrict__ xfrag) {
    int tid  = blockIdx.x * 256 + threadIdx.x;   // 4*128*16*64 = 524,288 threads
    int lane = tid & 63;
    int ks   = (tid >> 6) & 15;
    int nt   = (tid >> 10) & 127;
    int b    = tid >> 17;

    int n  = nt * 32 + (lane & 31);
    int c0 = ks * 16 + (lane >> 5) * 8;
    int hp = n >> 6, wp = n & 63;

    const float* xb = x + (size_t)b * CC * (HH * WW) + (2 * hp) * WW + 2 * wp;
    ushort4 lo, hi;
    unsigned short r[8];
    #pragma unroll
    for (int e = 0; e < 8; e++) {
        const float* src = xb + (size_t)(c0 + e) * (HH * WW);
        float2 a = *(const float2*)(src);
        float2 d = *(const float2*)(src + WW);
        r[e] = f2bf(0.25f * (a.x + a.y + d.x + d.y));
    }
    lo = (ushort4){r[0], r[1], r[2], r[3]};
    hi = (ushort4){r[4], r[5], r[6], r[7]};
    *(ushort4*)(xfrag + (size_t)tid * 8)     = lo;
    *(ushort4*)(xfrag + (size_t)tid * 8 + 4) = hi;
}

// ---------------------------------------------------------------------------
// K2a: one-time W -> A-fragment reorder (bf16), Q rows pre-scaled by log2(e).
// ---------------------------------------------------------------------------
__global__ __launch_bounds__(256) void wprep_kernel(const float* __restrict__ wq,
                                                    const float* __restrict__ wk,
                                                    const float* __restrict__ wv,
                                                    unsigned short* __restrict__ wfrag) {
    int tid  = blockIdx.x * 256 + threadIdx.x;   // 10*16*64 = 10,240 threads
    if (tid >= 10240) return;
    int lane = tid & 63;
    int ks   = (tid >> 6) & 15;
    int ot   = tid >> 10;

    int o = ot * 32 + (lane & 31);
    int c = ks * 16 + (lane >> 5) * 8;
    const float* wrow;
    float scale = 1.0f;
    if (o < 32)      { wrow = wq + (size_t)o * CC;        scale = L2E; }
    else if (o < 64) { wrow = wk + (size_t)(o - 32) * CC; }
    else             { wrow = wv + (size_t)(o - 64) * CC; }
    float4 w0 = *(const float4*)(wrow + c);
    float4 w1 = *(const float4*)(wrow + c + 4);
    ushort4 lo = {f2bf(w0.x * scale), f2bf(w0.y * scale), f2bf(w0.z * scale), f2bf(w0.w * scale)};
    ushort4 hi = {f2bf(w1.x * scale), f2bf(w1.y * scale), f2bf(w1.z * scale), f2bf(w1.w * scale)};
    *(ushort4*)(wfrag + (size_t)tid * 8)     = lo;
    *(ushort4*)(wfrag + (size_t)tid * 8 + 4) = hi;
}

// ---------------------------------------------------------------------------
// K2b: MFMA projection GEMM. Block = 2 waves; wave computes one 32o x 32n
// tile over K=256 (16 MFMA). All operand loads are contiguous 1KB/wave.
// Epilogue adds bias and scatter-stores into Q2/K2/V2 fragment layouts.
// ---------------------------------------------------------------------------
__global__ __launch_bounds__(128) void projm_kernel(const unsigned short* __restrict__ xfrag,
                                                    const unsigned short* __restrict__ wfrag,
                                                    const float* __restrict__ bq,
                                                    const float* __restrict__ bk,
                                                    const float* __restrict__ bv,
                                                    unsigned short* __restrict__ qarr,
                                                    unsigned short* __restrict__ karr,
                                                    unsigned short* __restrict__ varr) {
    int j    = blockIdx.x;            // 4b * 128nt * 5og = 2560
    int og   = j % 5;
    int nt   = (j / 5) & 127;
    int b    = j / 640;
    int lane = threadIdx.x & 63;
    int ot   = og * 2 + (threadIdx.x >> 6);   // 0..9

    const unsigned short* abase = wfrag + ((size_t)ot * 16 * 64 + lane) * 8;
    const unsigned short* bbase = xfrag + (((size_t)(b * 128 + nt) * 16) * 64 + lane) * 8;

    f32x16 acc;
    #pragma unroll
    for (int r = 0; r < 16; r++) acc[r] = 0.f;

    #pragma unroll
    for (int ks = 0; ks < 16; ks++) {
        bf16x8 af = *(const bf16x8*)(abase + (size_t)ks * 512);
        bf16x8 bf = *(const bf16x8*)(bbase + (size_t)ks * 512);
        acc = __builtin_amdgcn_mfma_f32_32x32x16_bf16(af, bf, acc, 0, 0, 0);
    }

    int l31 = lane & 31;
    int hi2 = lane >> 5;
    int n   = nt * 32 + l31;

    if (ot == 0) {
        // Q: o = crow, bias bq*L2E, write Q2
        unsigned short* qb = qarr + (size_t)b * (NP * 32);
        #pragma unroll
        for (int r = 0; r < 16; r++) {
            int o = (r & 3) + 8 * (r >> 2) + 4 * hi2;
            float v = acc[r] + bq[o] * L2E;
            size_t idx = (((size_t)nt * 2 + (o >> 4)) * 32 + l31) * 16 + ((o >> 3) & 1) * 8 + (o & 7);
            qb[idx] = f2bf(v);
        }
    } else if (ot == 1) {
        unsigned short* kb = karr + (size_t)b * (NP * 32);
        #pragma unroll
        for (int r = 0; r < 16; r++) {
            int o = (r & 3) + 8 * (r >> 2) + 4 * hi2;
            float v = acc[r] + bk[o];
            size_t idx = (((size_t)nt * 2 + (o >> 4)) * 32 + l31) * 16 + ((o >> 3) & 1) * 8 + (o & 7);
            kb[idx] = f2bf(v);
        }
    } else {
        unsigned short* vb = varr + (size_t)b * (CC * NP);
        int kc = nt, w2 = (l31 >> 4) & 1, hiv = (l31 >> 3) & 1, ev = l31 & 7;
        size_t base = (((size_t)kc * 2 + w2) * 8) * 32 * 16 + hiv * 8 + ev;
        #pragma unroll
        for (int r = 0; r < 16; r++) {
            int c = (ot - 2) * 32 + (r & 3) + 8 * (r >> 2) + 4 * hi2;
            float v = acc[r] + bv[c];
            size_t idx = base + ((size_t)(c >> 5) * 32 + (c & 31)) * 16;
            vb[idx] = f2bf(v);
        }
    }
}

// ---------------------------------------------------------------------------
// K3: swapped-operand 32x32 MFMA flash attention, FULL-CHANNEL waves.
// (unchanged from R12: 74us, absmax-verified)
// ---------------------------------------------------------------------------
__global__ __launch_bounds__(256, 2) void flash32_kernel(const unsigned short* __restrict__ qarr,
                                                         const unsigned short* __restrict__ karr,
                                                         const unsigned short* __restrict__ varr,
                                                         float* __restrict__ att) {
    __shared__ float cacc[64][136];    // combine: one wave's 128 acc f32 per lane
    __shared__ float cml[64][2];       // combine: m, l per lane
    int t    = threadIdx.x;
    int lane = t & 63;
    int ks   = t >> 6;                 // 0..3 key quarter
    int j    = blockIdx.x;
    int b    = j & 3;                  // batch -> XCD pinning
    int qt   = j >> 2;                 // 0..127 q-tile (32 rows)

    const unsigned short* qb2 = qarr + (size_t)b * (NP * 32);
    const unsigned short* kb2 = karr + (size_t)b * (NP * 32);
    const unsigned short* vb2 = varr + (size_t)b * (CC * NP);

    int q  = lane & 31;
    int hi = lane >> 5;
    int lq16 = (q * 2 + hi) * 8;       // lane's 16B slot within a 1KB fragment block

    bf16x8 qf0 = *(const bf16x8*)(qb2 + (size_t)(qt * 2 + 0) * 512 + lq16);
    bf16x8 qf1 = *(const bf16x8*)(qb2 + (size_t)(qt * 2 + 1) * 512 + lq16);

    f32x16 acc[8];
    #pragma unroll
    for (int ct = 0; ct < 8; ct++)
        #pragma unroll
        for (int r = 0; r < 16; r++) acc[ct][r] = 0.f;
    float mrun = -3.0e38f, lrun = 0.f;

    const f32x16 z16 = {0.f,0.f,0.f,0.f,0.f,0.f,0.f,0.f,0.f,0.f,0.f,0.f,0.f,0.f,0.f,0.f};

    for (int kci = 0; kci < 32; ++kci) {
        int kcidx = ks * 32 + kci;

        const unsigned short* kcp = kb2 + (size_t)kcidx * 1024 + lq16;
        bf16x8 kf0 = *(const bf16x8*)(kcp);
        bf16x8 kf1 = *(const bf16x8*)(kcp + 512);
        f32x16 s = __builtin_amdgcn_mfma_f32_32x32x16_bf16(kf0, qf0, z16, 0, 0, 0);
        s = __builtin_amdgcn_mfma_f32_32x32x16_bf16(kf1, qf1, s, 0, 0, 0);

        float m01 = fmaxf(s[0], s[1]),   m23 = fmaxf(s[2], s[3]);
        float m45 = fmaxf(s[4], s[5]),   m67 = fmaxf(s[6], s[7]);
        float m89 = fmaxf(s[8], s[9]),   mab = fmaxf(s[10], s[11]);
        float mcd = fmaxf(s[12], s[13]), mef = fmaxf(s[14], s[15]);
        float mx = fmaxf(fmaxf(fmaxf(m01, m23), fmaxf(m45, m67)),
                         fmaxf(fmaxf(m89, mab), fmaxf(mcd, mef)));
        mx = fmaxf(mx, __shfl_xor(mx, 32, 64));

        if (!__all(mx - mrun <= 11.5f)) {
            float mn = fmaxf(mrun, mx);
            float sc = exp2fast(mrun - mn);
            mrun = mn;
            lrun *= sc;
            #pragma unroll
            for (int ct = 0; ct < 8; ct++)
                #pragma unroll
                for (int r = 0; r < 16; r++) acc[ct][r] *= sc;
        }

        unsigned int pkr[8];
        float ss = 0.f;
        #pragma unroll
        for (int r2 = 0; r2 < 8; r2++) {
            float p0 = exp2fast(s[2 * r2]     - mrun);
            float p1 = exp2fast(s[2 * r2 + 1] - mrun);
            ss += p0 + p1;
            pkr[r2] = pk2(p0, p1);
        }
        ss += __shfl_xor(ss, 32, 64);
        lrun += ss;

        #pragma unroll
        for (int w2 = 0; w2 < 2; w2++) {
            unsigned int a0 = pkr[4 * w2 + 0], a1 = pkr[4 * w2 + 1];
            unsigned int c0 = pkr[4 * w2 + 2], c1 = pkr[4 * w2 + 3];
            unsigned int sa0 = __shfl_xor(a0, 32, 64), sa1 = __shfl_xor(a1, 32, 64);
            unsigned int sc0 = __shfl_xor(c0, 32, 64), sc1 = __shfl_xor(c1, 32, 64);
            u32x4 fr;
            if (hi == 0) { fr[0] = a0;  fr[1] = a1;  fr[2] = sa0; fr[3] = sa1; }
            else         { fr[0] = sc0; fr[1] = sc1; fr[2] = c0;  fr[3] = c1;  }
            bf16x8 pf = __builtin_bit_cast(bf16x8, fr);
            const unsigned short* vcp = vb2 + ((size_t)kcidx * 16 + w2 * 8) * 512 + lq16;
            #pragma unroll
            for (int ct = 0; ct < 8; ct++) {
                bf16x8 vf = *(const bf16x8*)(vcp + (size_t)ct * 512);
                acc[ct] = __builtin_amdgcn_mfma_f32_32x32x16_bf16(vf, pf, acc[ct], 0, 0, 0);
            }
        }
    }

    for (int sIdx = 3; sIdx >= 1; --sIdx) {
        if (ks == sIdx) {
            #pragma unroll
            for (int ct = 0; ct < 8; ct++)
                #pragma unroll
                for (int rr = 0; rr < 4; rr++) {
                    float4 v4 = {acc[ct][rr*4+0], acc[ct][rr*4+1], acc[ct][rr*4+2], acc[ct][rr*4+3]};
                    *(float4*)&cacc[lane][ct * 16 + rr * 4] = v4;
                }
            cml[lane][0] = mrun; cml[lane][1] = lrun;
        }
        __syncthreads();
        if (ks == 0) {
            float mo = cml[lane][0];
            float lo = cml[lane][1];
            float mn = fmaxf(mrun, mo);
            float e0 = exp2fast(mrun - mn);
            float e1 = exp2fast(mo - mn);
            mrun = mn;
            lrun = lrun * e0 + lo * e1;
            #pragma unroll
            for (int ct = 0; ct < 8; ct++)
                #pragma unroll
                for (int r = 0; r < 16; r++)
                    acc[ct][r] = acc[ct][r] * e0 + cacc[lane][ct * 16 + r] * e1;
        }
        __syncthreads();
    }

    if (ks == 0) {
        float inv = 1.0f / lrun;
        #pragma unroll
        for (int ct = 0; ct < 8; ct++)
            #pragma unroll
            for (int r = 0; r < 16; r++) {
                int c = ct * 32 + (r & 3) + 8 * (r >> 2) + 4 * hi;
                att[((size_t)b * CC + c) * NP + qt * 32 + q] = acc[ct][r] * inv;
            }
    }
}

// ---------------------------------------------------------------------------
// K4: bilinear x2 upsample (half-pixel, edge clamp) + gamma * up + x, x4 vec
// ---------------------------------------------------------------------------
__global__ __launch_bounds__(256) void upsample_kernel(const float* __restrict__ att,
                                                       const float* __restrict__ x,
                                                       const float* __restrict__ gamma,
                                                       float* __restrict__ out) {
    int tid = blockIdx.x * 256 + threadIdx.x;    // B*C*H*W/4 threads
    int w4 = (tid & 31) * 4;
    int h  = (tid >> 5) & 127;
    int bc = tid >> 12;
    float g = gamma[0];

    float sh = 0.5f * h - 0.25f;
    float fhf = floorf(sh);
    float th = sh - fhf;
    int ih = (int)fhf;
    int ih0 = ih < 0 ? 0 : ih;
    int ih1 = ih + 1 > 63 ? 63 : ih + 1;
    const float* a0r = att + (size_t)bc * NP + ih0 * 64;
    const float* a1r = att + (size_t)bc * NP + ih1 * 64;

    float4 xin = *(const float4*)(x + (size_t)bc * (HH * WW) + h * WW + w4);
    float xv[4] = {xin.x, xin.y, xin.z, xin.w};
    float ov[4];
    #pragma unroll
    for (int k = 0; k < 4; k++) {
        int w = w4 + k;
        float sw = 0.5f * w - 0.25f;
        float fwf = floorf(sw);
        float tw = sw - fwf;
        int iw = (int)fwf;
        int iw0 = iw < 0 ? 0 : iw;
        int iw1 = iw + 1 > 63 ? 63 : iw + 1;
        float v00 = a0r[iw0], v01 = a0r[iw1];
        float v10 = a1r[iw0], v11 = a1r[iw1];
        float top = v00 + tw * (v01 - v00);
        float bot = v10 + tw * (v11 - v10);
        float up  = top + th * (bot - top);
        ov[k] = g * up + xv[k];
    }
    float4 o4 = {ov[0], ov[1], ov[2], ov[3]};
    *(float4*)(out + (size_t)bc * (HH * WW) + h * WW + w4) = o4;
}

// ---------------------------------------------------------------------------
extern "C" void kernel_launch(void* const* d_in, const int* in_sizes, int n_in,
                              void* d_out, int out_size, void* d_ws, size_t ws_size,
                              hipStream_t stream) {
    (void)in_sizes; (void)n_in; (void)out_size; (void)ws_size;
    const float* x     = (const float*)d_in[0];
    const float* wq    = (const float*)d_in[1];
    const float* bq    = (const float*)d_in[2];
    const float* wk    = (const float*)d_in[3];
    const float* bk    = (const float*)d_in[4];
    const float* wv    = (const float*)d_in[5];
    const float* bv    = (const float*)d_in[6];
    const float* gamma = (const float*)d_in[7];
    float* out = (float*)d_out;

    unsigned short* xfrag = (unsigned short*)d_ws;             // 4,194,304 u16 (8 MB)
    unsigned short* wfrag = xfrag + 4194304;                   // 81,920 u16 (pad to 131,072)
    unsigned short* qarr  = wfrag + 131072;                    // 524,288 u16 (1 MB)
    unsigned short* karr  = qarr + 524288;                     // 524,288 u16 (1 MB)
    unsigned short* varr  = karr + 524288;                     // 4,194,304 u16 (8 MB)
    float*          att   = (float*)(varr + 4194304);          // 4,194,304 f32 (16 MB)

    pool2_kernel<<<2048, 256, 0, stream>>>(x, xfrag);
    wprep_kernel<<<40, 256, 0, stream>>>(wq, wk, wv, wfrag);
    projm_kernel<<<2560, 128, 0, stream>>>(xfrag, wfrag, bq, bk, bv, qarr, karr, varr);
    flash32_kernel<<<512, 256, 0, stream>>>(qarr, karr, varr, att);
    upsample_kernel<<<16384, 256, 0, stream>>>(att, x, gamma, out);
}

// Round 14
// 125.692 us; speedup vs baseline: 1.3313x; 1.0579x over previous
//
#include <hip/hip_runtime.h>

// Sizes (fixed by the problem)
#define BB 4
#define CC 256
#define HH 128
#define WW 128
#define HP 64          // pooled H, W
#define NP 4096        // HP*HP tokens per batch

#define L2E 1.4426950408889634f

typedef __attribute__((ext_vector_type(4)))  float f32x4;
typedef __attribute__((ext_vector_type(16))) float f32x16;
typedef __attribute__((ext_vector_type(8)))  short bf16x8;       // 8 bf16 in 4 VGPRs
typedef __attribute__((ext_vector_type(4)))  unsigned int u32x4;

// 2^x via v_exp_f32 (native). NOT __exp2f: that name collides with glibc macros.
static __device__ __forceinline__ float exp2fast(float x) {
    return __builtin_amdgcn_exp2f(x);
}

// float -> bf16 bits, round-to-nearest-even. Reference-matching. (R9's __bf16
// cast and R9/R10's PERMSWAP inline-asm both perturbed absmax — stay on the
// shfl_xor + bit-trick path.)
static __device__ __forceinline__ unsigned short f2bf(float f) {
    unsigned int u = __float_as_uint(f);
    u = (u + 0x7FFFu + ((u >> 16) & 1u)) >> 16;
    return (unsigned short)u;
}
static __device__ __forceinline__ unsigned int pk2(float a, float b) {
    return (unsigned int)f2bf(a) | ((unsigned int)f2bf(b) << 16);
}

// ---------------------------------------------------------------------------
// Fragment-ordered layouts (bf16):
//   xfrag[b][nt(128)][ks(16)][lane(64)][e(8)] : B-frag, X[c][n]
//   wfrag[ot(10)][ks(16)][lane(64)][e(8)]     : A-frag, W[o][c] (Q rows xL2E)
//   Q2[qtile(128)][f(2)][q(32)][hi(2)][e(8)]
//   K2[kchunk(128)][f(2)][k(32)][hi(2)][e(8)]
//   V2[kc(128)][w2(2)][ctg(8)][q(32)][hi(2)][e(8)]
// mfma_32x32x16_bf16 (m74/m101): A row=lane&31, k=(lane>>5)*8+e; B col=lane&31,
// same k; D col=lane&31, row=(r&3)+8*(r>>2)+4*(lane>>5).
// ---------------------------------------------------------------------------

// ---------------------------------------------------------------------------
// K1: fused 2x2 avg-pool + bf16 B-fragment layout. One thread = one 16B slot.
// ---------------------------------------------------------------------------
__global__ __launch_bounds__(256) void pool2_kernel(const float* __restrict__ x,
                                                    unsigned short* __restrict__ xfrag) {
    int tid  = blockIdx.x * 256 + threadIdx.x;   // 4*128*16*64 = 524,288 threads
    int lane = tid & 63;
    int ks   = (tid >> 6) & 15;
    int nt   = (tid >> 10) & 127;
    int b    = tid >> 17;

    int n  = nt * 32 + (lane & 31);
    int c0 = ks * 16 + (lane >> 5) * 8;
    int hp = n >> 6, wp = n & 63;

    const float* xb = x + (size_t)b * CC * (HH * WW) + (2 * hp) * WW + 2 * wp;
    ushort4 lo, hi;
    unsigned short r[8];
    #pragma unroll
    for (int e = 0; e < 8; e++) {
        const float* src = xb + (size_t)(c0 + e) * (HH * WW);
        float2 a = *(const float2*)(src);
        float2 d = *(const float2*)(src + WW);
        r[e] = f2bf(0.25f * (a.x + a.y + d.x + d.y));
    }
    lo = (ushort4){r[0], r[1], r[2], r[3]};
    hi = (ushort4){r[4], r[5], r[6], r[7]};
    *(ushort4*)(xfrag + (size_t)tid * 8)     = lo;
    *(ushort4*)(xfrag + (size_t)tid * 8 + 4) = hi;
}

// ---------------------------------------------------------------------------
// K2a: one-time W -> A-fragment reorder (bf16), Q rows pre-scaled by log2(e).
// ---------------------------------------------------------------------------
__global__ __launch_bounds__(256) void wprep_kernel(const float* __restrict__ wq,
                                                    const float* __restrict__ wk,
                                                    const float* __restrict__ wv,
                                                    unsigned short* __restrict__ wfrag) {
    int tid  = blockIdx.x * 256 + threadIdx.x;   // 10*16*64 = 10,240 threads
    if (tid >= 10240) return;
    int lane = tid & 63;
    int ks   = (tid >> 6) & 15;
    int ot   = tid >> 10;

    int o = ot * 32 + (lane & 31);
    int c = ks * 16 + (lane >> 5) * 8;
    const float* wrow;
    float scale = 1.0f;
    if (o < 32)      { wrow = wq + (size_t)o * CC;        scale = L2E; }
    else if (o < 64) { wrow = wk + (size_t)(o - 32) * CC; }
    else             { wrow = wv + (size_t)(o - 64) * CC; }
    float4 w0 = *(const float4*)(wrow + c);
    float4 w1 = *(const float4*)(wrow + c + 4);
    ushort4 lo = {f2bf(w0.x * scale), f2bf(w0.y * scale), f2bf(w0.z * scale), f2bf(w0.w * scale)};
    ushort4 hi = {f2bf(w1.x * scale), f2bf(w1.y * scale), f2bf(w1.z * scale), f2bf(w1.w * scale)};
    *(ushort4*)(wfrag + (size_t)tid * 8)     = lo;
    *(ushort4*)(wfrag + (size_t)tid * 8 + 4) = hi;
}

// ---------------------------------------------------------------------------
// K2b: MFMA projection GEMM. Block = 2 waves; wave computes one 32o x 32n
// tile over K=256 (16 MFMA). All operand loads are contiguous 1KB/wave.
// Epilogue adds bias and scatter-stores into Q2/K2/V2 fragment layouts.
// ---------------------------------------------------------------------------
__global__ __launch_bounds__(128) void projm_kernel(const unsigned short* __restrict__ xfrag,
                                                    const unsigned short* __restrict__ wfrag,
                                                    const float* __restrict__ bq,
                                                    const float* __restrict__ bk,
                                                    const float* __restrict__ bv,
                                                    unsigned short* __restrict__ qarr,
                                                    unsigned short* __restrict__ karr,
                                                    unsigned short* __restrict__ varr) {
    int j    = blockIdx.x;            // 4b * 128nt * 5og = 2560
    int og   = j % 5;
    int nt   = (j / 5) & 127;
    int b    = j / 640;
    int lane = threadIdx.x & 63;
    int ot   = og * 2 + (threadIdx.x >> 6);   // 0..9

    const unsigned short* abase = wfrag + ((size_t)ot * 16 * 64 + lane) * 8;
    const unsigned short* bbase = xfrag + (((size_t)(b * 128 + nt) * 16) * 64 + lane) * 8;

    f32x16 acc;
    #pragma unroll
    for (int r = 0; r < 16; r++) acc[r] = 0.f;

    #pragma unroll
    for (int ks = 0; ks < 16; ks++) {
        bf16x8 af = *(const bf16x8*)(abase + (size_t)ks * 512);
        bf16x8 bf = *(const bf16x8*)(bbase + (size_t)ks * 512);
        acc = __builtin_amdgcn_mfma_f32_32x32x16_bf16(af, bf, acc, 0, 0, 0);
    }

    int l31 = lane & 31;
    int hi2 = lane >> 5;

    if (ot == 0) {
        unsigned short* qb = qarr + (size_t)b * (NP * 32);
        #pragma unroll
        for (int r = 0; r < 16; r++) {
            int o = (r & 3) + 8 * (r >> 2) + 4 * hi2;
            float v = acc[r] + bq[o] * L2E;
            size_t idx = (((size_t)nt * 2 + (o >> 4)) * 32 + l31) * 16 + ((o >> 3) & 1) * 8 + (o & 7);
            qb[idx] = f2bf(v);
        }
    } else if (ot == 1) {
        unsigned short* kb = karr + (size_t)b * (NP * 32);
        #pragma unroll
        for (int r = 0; r < 16; r++) {
            int o = (r & 3) + 8 * (r >> 2) + 4 * hi2;
            float v = acc[r] + bk[o];
            size_t idx = (((size_t)nt * 2 + (o >> 4)) * 32 + l31) * 16 + ((o >> 3) & 1) * 8 + (o & 7);
            kb[idx] = f2bf(v);
        }
    } else {
        unsigned short* vb = varr + (size_t)b * (CC * NP);
        int kc = nt, w2 = (l31 >> 4) & 1, hiv = (l31 >> 3) & 1, ev = l31 & 7;
        size_t base = (((size_t)kc * 2 + w2) * 8) * 32 * 16 + hiv * 8 + ev;
        #pragma unroll
        for (int r = 0; r < 16; r++) {
            int c = (ot - 2) * 32 + (r & 3) + 8 * (r >> 2) + 4 * hi2;
            float v = acc[r] + bv[c];
            size_t idx = base + ((size_t)(c >> 5) * 32 + (c & 31)) * 16;
            vb[idx] = f2bf(v);
        }
    }
}

// ---------------------------------------------------------------------------
// K3: swapped-operand 32x32 MFMA flash attention, FULL-CHANNEL waves +
// explicit load hoisting: all 16 V frag loads issue BEFORE softmax (use after
// softmax -> ~270cy of QK+softmax covers L2 latency), K prefetched one chunk
// ahead. Unconfounded retest of R10's prefetch (occupancy unchanged: 2/SIMD).
// ---------------------------------------------------------------------------
__global__ __launch_bounds__(256, 2) void flash32_kernel(const unsigned short* __restrict__ qarr,
                                                         const unsigned short* __restrict__ karr,
                                                         const unsigned short* __restrict__ varr,
                                                         float* __restrict__ att) {
    __shared__ float cacc[64][136];    // combine: one wave's 128 acc f32 per lane
    __shared__ float cml[64][2];       // combine: m, l per lane
    int t    = threadIdx.x;
    int lane = t & 63;
    int ks   = t >> 6;                 // 0..3 key quarter
    int j    = blockIdx.x;
    int b    = j & 3;                  // batch -> XCD pinning
    int qt   = j >> 2;                 // 0..127 q-tile (32 rows)

    const unsigned short* qb2 = qarr + (size_t)b * (NP * 32);
    const unsigned short* kb2 = karr + (size_t)b * (NP * 32);
    const unsigned short* vb2 = varr + (size_t)b * (CC * NP);

    int q  = lane & 31;
    int hi = lane >> 5;
    int lq16 = (q * 2 + hi) * 8;       // lane's 16B slot within a 1KB fragment block

    bf16x8 qf0 = *(const bf16x8*)(qb2 + (size_t)(qt * 2 + 0) * 512 + lq16);
    bf16x8 qf1 = *(const bf16x8*)(qb2 + (size_t)(qt * 2 + 1) * 512 + lq16);

    f32x16 acc[8];
    #pragma unroll
    for (int ct = 0; ct < 8; ct++)
        #pragma unroll
        for (int r = 0; r < 16; r++) acc[ct][r] = 0.f;
    float mrun = -3.0e38f, lrun = 0.f;

    const f32x16 z16 = {0.f,0.f,0.f,0.f,0.f,0.f,0.f,0.f,0.f,0.f,0.f,0.f,0.f,0.f,0.f,0.f};

    // ---- prologue: K frags for first chunk
    int kc0 = ks * 32;
    const unsigned short* kcp0 = kb2 + (size_t)kc0 * 1024 + lq16;
    bf16x8 kcur0 = *(const bf16x8*)(kcp0);
    bf16x8 kcur1 = *(const bf16x8*)(kcp0 + 512);

    for (int kci = 0; kci < 32; ++kci) {
        int kcidx = kc0 + kci;

        // ---- issue all 16 V loads for THIS chunk (consumed after softmax)
        const unsigned short* vcp = vb2 + ((size_t)kcidx * 16) * 512 + lq16;
        bf16x8 vf[16];
        #pragma unroll
        for (int i = 0; i < 16; i++)
            vf[i] = *(const bf16x8*)(vcp + (size_t)i * 512);

        // ---- issue K loads for NEXT chunk (consumed next iteration)
        int nid = (kci < 31) ? (kcidx + 1) : kcidx;
        const unsigned short* kn = kb2 + (size_t)nid * 1024 + lq16;
        bf16x8 kn0 = *(const bf16x8*)(kn);
        bf16x8 kn1 = *(const bf16x8*)(kn + 512);

        // ---- QK^T swapped (operands already in registers)
        f32x16 s = __builtin_amdgcn_mfma_f32_32x32x16_bf16(kcur0, qf0, z16, 0, 0, 0);
        s = __builtin_amdgcn_mfma_f32_32x32x16_bf16(kcur1, qf1, s, 0, 0, 0);

        // ---- in-lane max over 16 keys + 1 cross-half swap
        float m01 = fmaxf(s[0], s[1]),   m23 = fmaxf(s[2], s[3]);
        float m45 = fmaxf(s[4], s[5]),   m67 = fmaxf(s[6], s[7]);
        float m89 = fmaxf(s[8], s[9]),   mab = fmaxf(s[10], s[11]);
        float mcd = fmaxf(s[12], s[13]), mef = fmaxf(s[14], s[15]);
        float mx = fmaxf(fmaxf(fmaxf(m01, m23), fmaxf(m45, m67)),
                         fmaxf(fmaxf(m89, mab), fmaxf(mcd, mef)));
        mx = fmaxf(mx, __shfl_xor(mx, 32, 64));

        // ---- defer-max (T13, log2 domain)
        if (!__all(mx - mrun <= 11.5f)) {
            float mn = fmaxf(mrun, mx);
            float sc = exp2fast(mrun - mn);
            mrun = mn;
            lrun *= sc;
            #pragma unroll
            for (int ct = 0; ct < 8; ct++)
                #pragma unroll
                for (int r = 0; r < 16; r++) acc[ct][r] *= sc;
        }

        // ---- P = exp2(S^T - m): pack pairs (bit-exact RNE)
        unsigned int pkr[8];
        float ss = 0.f;
        #pragma unroll
        for (int r2 = 0; r2 < 8; r2++) {
            float p0 = exp2fast(s[2 * r2]     - mrun);
            float p1 = exp2fast(s[2 * r2 + 1] - mrun);
            ss += p0 + p1;
            pkr[r2] = pk2(p0, p1);
        }
        ss += __shfl_xor(ss, 32, 64);
        lrun += ss;

        // ---- PV: V frags already in flight/registers
        #pragma unroll
        for (int w2 = 0; w2 < 2; w2++) {
            unsigned int a0 = pkr[4 * w2 + 0], a1 = pkr[4 * w2 + 1];
            unsigned int c0 = pkr[4 * w2 + 2], c1 = pkr[4 * w2 + 3];
            unsigned int sa0 = __shfl_xor(a0, 32, 64), sa1 = __shfl_xor(a1, 32, 64);
            unsigned int sc0 = __shfl_xor(c0, 32, 64), sc1 = __shfl_xor(c1, 32, 64);
            u32x4 fr;
            if (hi == 0) { fr[0] = a0;  fr[1] = a1;  fr[2] = sa0; fr[3] = sa1; }
            else         { fr[0] = sc0; fr[1] = sc1; fr[2] = c0;  fr[3] = c1;  }
            bf16x8 pf = __builtin_bit_cast(bf16x8, fr);
            #pragma unroll
            for (int ct = 0; ct < 8; ct++) {
                acc[ct] = __builtin_amdgcn_mfma_f32_32x32x16_bf16(vf[w2 * 8 + ct], pf, acc[ct], 0, 0, 0);
            }
        }

        kcur0 = kn0; kcur1 = kn1;
    }

    // ---- split-K combine: ks 3,2,1 hand state to ks 0 (elementwise per lane)
    for (int sIdx = 3; sIdx >= 1; --sIdx) {
        if (ks == sIdx) {
            #pragma unroll
            for (int ct = 0; ct < 8; ct++)
                #pragma unroll
                for (int rr = 0; rr < 4; rr++) {
                    float4 v4 = {acc[ct][rr*4+0], acc[ct][rr*4+1], acc[ct][rr*4+2], acc[ct][rr*4+3]};
                    *(float4*)&cacc[lane][ct * 16 + rr * 4] = v4;
                }
            cml[lane][0] = mrun; cml[lane][1] = lrun;
        }
        __syncthreads();
        if (ks == 0) {
            float mo = cml[lane][0];
            float lo = cml[lane][1];
            float mn = fmaxf(mrun, mo);
            float e0 = exp2fast(mrun - mn);
            float e1 = exp2fast(mo - mn);
            mrun = mn;
            lrun = lrun * e0 + lo * e1;
            #pragma unroll
            for (int ct = 0; ct < 8; ct++)
                #pragma unroll
                for (int r = 0; r < 16; r++)
                    acc[ct][r] = acc[ct][r] * e0 + cacc[lane][ct * 16 + r] * e1;
        }
        __syncthreads();
    }

    if (ks == 0) {
        float inv = 1.0f / lrun;
        #pragma unroll
        for (int ct = 0; ct < 8; ct++)
            #pragma unroll
            for (int r = 0; r < 16; r++) {
                int c = ct * 32 + (r & 3) + 8 * (r >> 2) + 4 * hi;
                att[((size_t)b * CC + c) * NP + qt * 32 + q] = acc[ct][r] * inv;
            }
    }
}

// ---------------------------------------------------------------------------
// K4: bilinear x2 upsample (half-pixel, edge clamp) + gamma * up + x, x4 vec
// ---------------------------------------------------------------------------
__global__ __launch_bounds__(256) void upsample_kernel(const float* __restrict__ att,
                                                       const float* __restrict__ x,
                                                       const float* __restrict__ gamma,
                                                       float* __restrict__ out) {
    int tid = blockIdx.x * 256 + threadIdx.x;    // B*C*H*W/4 threads
    int w4 = (tid & 31) * 4;
    int h  = (tid >> 5) & 127;
    int bc = tid >> 12;
    float g = gamma[0];

    float sh = 0.5f * h - 0.25f;
    float fhf = floorf(sh);
    float th = sh - fhf;
    int ih = (int)fhf;
    int ih0 = ih < 0 ? 0 : ih;
    int ih1 = ih + 1 > 63 ? 63 : ih + 1;
    const float* a0r = att + (size_t)bc * NP + ih0 * 64;
    const float* a1r = att + (size_t)bc * NP + ih1 * 64;

    float4 xin = *(const float4*)(x + (size_t)bc * (HH * WW) + h * WW + w4);
    float xv[4] = {xin.x, xin.y, xin.z, xin.w};
    float ov[4];
    #pragma unroll
    for (int k = 0; k < 4; k++) {
        int w = w4 + k;
        float sw = 0.5f * w - 0.25f;
        float fwf = floorf(sw);
        float tw = sw - fwf;
        int iw = (int)fwf;
        int iw0 = iw < 0 ? 0 : iw;
        int iw1 = iw + 1 > 63 ? 63 : iw + 1;
        float v00 = a0r[iw0], v01 = a0r[iw1];
        float v10 = a1r[iw0], v11 = a1r[iw1];
        float top = v00 + tw * (v01 - v00);
        float bot = v10 + tw * (v11 - v10);
        float up  = top + th * (bot - top);
        ov[k] = g * up + xv[k];
    }
    float4 o4 = {ov[0], ov[1], ov[2], ov[3]};
    *(float4*)(out + (size_t)bc * (HH * WW) + h * WW + w4) = o4;
}

// ---------------------------------------------------------------------------
extern "C" void kernel_launch(void* const* d_in, const int* in_sizes, int n_in,
                              void* d_out, int out_size, void* d_ws, size_t ws_size,
                              hipStream_t stream) {
    (void)in_sizes; (void)n_in; (void)out_size; (void)ws_size;
    const float* x     = (const float*)d_in[0];
    const float* wq    = (const float*)d_in[1];
    const float* bq    = (const float*)d_in[2];
    const float* wk    = (const float*)d_in[3];
    const float* bk    = (const float*)d_in[4];
    const float* wv    = (const float*)d_in[5];
    const float* bv    = (const float*)d_in[6];
    const float* gamma = (const float*)d_in[7];
    float* out = (float*)d_out;

    unsigned short* xfrag = (unsigned short*)d_ws;             // 4,194,304 u16 (8 MB)
    unsigned short* wfrag = xfrag + 4194304;                   // 81,920 u16 (pad to 131,072)
    unsigned short* qarr  = wfrag + 131072;                    // 524,288 u16 (1 MB)
    unsigned short* karr  = qarr + 524288;                     // 524,288 u16 (1 MB)
    unsigned short* varr  = karr + 524288;                     // 4,194,304 u16 (8 MB)
    float*          att   = (float*)(varr + 4194304);          // 4,194,304 f32 (16 MB)

    pool2_kernel<<<2048, 256, 0, stream>>>(x, xfrag);
    wprep_kernel<<<40, 256, 0, stream>>>(wq, wk, wv, wfrag);
    projm_kernel<<<2560, 128, 0, stream>>>(xfrag, wfrag, bq, bk, bv, qarr, karr, varr);
    flash32_kernel<<<512, 256, 0, stream>>>(qarr, karr, varr, att);
    upsample_kernel<<<16384, 256, 0, stream>>>(att, x, gamma, out);
}

// Round 15
// 122.851 us; speedup vs baseline: 1.3621x; 1.0231x over previous
//
#include <hip/hip_runtime.h>

// Sizes (fixed by the problem)
#define BB 4
#define CC 256
#define HH 128
#define WW 128
#define HP 64          // pooled H, W
#define NP 4096        // HP*HP tokens per batch

#define L2E 1.4426950408889634f

typedef __attribute__((ext_vector_type(4)))  float f32x4;
typedef __attribute__((ext_vector_type(16))) float f32x16;
typedef __attribute__((ext_vector_type(8)))  short bf16x8;       // 8 bf16 in 4 VGPRs
typedef __attribute__((ext_vector_type(4)))  unsigned int u32x4;
typedef __attribute__((ext_vector_type(2)))  __bf16 bf16x2_t;

// 2^x via v_exp_f32 (native). NOT __exp2f: that name collides with glibc macros.
static __device__ __forceinline__ float exp2fast(float x) {
    return __builtin_amdgcn_exp2f(x);
}

// float -> bf16 bits, round-to-nearest-even bit-trick (used on proj/pool paths).
static __device__ __forceinline__ unsigned short f2bf(float f) {
    unsigned int u = __float_as_uint(f);
    u = (u + 0x7FFFu + ((u >> 16) & 1u)) >> 16;
    return (unsigned short)u;
}
// flash P-pack: compiler-fused v_cvt_pk_bf16_f32 (plain casts, no asm — m240).
// Isolated numerics change vs R14 (PERMSWAP, the prior absmax culprit, is gone).
static __device__ __forceinline__ unsigned int pk2(float a, float b) {
    bf16x2_t v = {(__bf16)a, (__bf16)b};
    return __builtin_bit_cast(unsigned int, v);
}

// ---------------------------------------------------------------------------
// Fragment-ordered layouts (bf16):
//   xfrag[b][nt(128)][ks(16)][lane(64)][e(8)] : B-frag, X[c][n]
//   wfrag[ot(10)][ks(16)][lane(64)][e(8)]     : A-frag, W[o][c] (Q rows xL2E)
//   Q2[qtile(128)][f(2)][q(32)][hi(2)][e(8)]
//   K2[kchunk(128)][f(2)][k(32)][hi(2)][e(8)]
//   V2[kc(128)][w2(2)][ctg(8)][q(32)][hi(2)][e(8)]
// mfma_32x32x16_bf16 (m74/m101): A row=lane&31, k=(lane>>5)*8+e; B col=lane&31,
// same k; D col=lane&31, row=(r&3)+8*(r>>2)+4*(lane>>5).
// ---------------------------------------------------------------------------

// ---------------------------------------------------------------------------
// K1: fused 2x2 avg-pool + bf16 B-fragment layout, PLUS (blocks >= 2048)
// the one-time W -> A-fragment reorder (merged to save a launch).
// ---------------------------------------------------------------------------
__global__ __launch_bounds__(256) void prep_kernel(const float* __restrict__ x,
                                                   const float* __restrict__ wq,
                                                   const float* __restrict__ wk,
                                                   const float* __restrict__ wv,
                                                   unsigned short* __restrict__ xfrag,
                                                   unsigned short* __restrict__ wfrag) {
    if (blockIdx.x < 2048) {
        int tid  = blockIdx.x * 256 + threadIdx.x;   // 4*128*16*64 = 524,288 threads
        int lane = tid & 63;
        int ks   = (tid >> 6) & 15;
        int nt   = (tid >> 10) & 127;
        int b    = tid >> 17;

        int n  = nt * 32 + (lane & 31);
        int c0 = ks * 16 + (lane >> 5) * 8;
        int hp = n >> 6, wp = n & 63;

        const float* xb = x + (size_t)b * CC * (HH * WW) + (2 * hp) * WW + 2 * wp;
        unsigned short r[8];
        #pragma unroll
        for (int e = 0; e < 8; e++) {
            const float* src = xb + (size_t)(c0 + e) * (HH * WW);
            float2 a = *(const float2*)(src);
            float2 d = *(const float2*)(src + WW);
            r[e] = f2bf(0.25f * (a.x + a.y + d.x + d.y));
        }
        ushort4 lo = (ushort4){r[0], r[1], r[2], r[3]};
        ushort4 hi = (ushort4){r[4], r[5], r[6], r[7]};
        *(ushort4*)(xfrag + (size_t)tid * 8)     = lo;
        *(ushort4*)(xfrag + (size_t)tid * 8 + 4) = hi;
    } else {
        int tid  = (blockIdx.x - 2048) * 256 + threadIdx.x;   // 10*16*64 = 10,240
        if (tid >= 10240) return;
        int lane = tid & 63;
        int ks   = (tid >> 6) & 15;
        int ot   = tid >> 10;

        int o = ot * 32 + (lane & 31);
        int c = ks * 16 + (lane >> 5) * 8;
        const float* wrow;
        float scale = 1.0f;
        if (o < 32)      { wrow = wq + (size_t)o * CC;        scale = L2E; }
        else if (o < 64) { wrow = wk + (size_t)(o - 32) * CC; }
        else             { wrow = wv + (size_t)(o - 64) * CC; }
        float4 w0 = *(const float4*)(wrow + c);
        float4 w1 = *(const float4*)(wrow + c + 4);
        ushort4 lo = {f2bf(w0.x * scale), f2bf(w0.y * scale), f2bf(w0.z * scale), f2bf(w0.w * scale)};
        ushort4 hi = {f2bf(w1.x * scale), f2bf(w1.y * scale), f2bf(w1.z * scale), f2bf(w1.w * scale)};
        *(ushort4*)(wfrag + (size_t)tid * 8)     = lo;
        *(ushort4*)(wfrag + (size_t)tid * 8 + 4) = hi;
    }
}

// ---------------------------------------------------------------------------
// K2: MFMA projection GEMM. Block = 2 waves; wave computes one 32o x 32n
// tile over K=256 (16 MFMA). All operand loads are contiguous 1KB/wave.
// Epilogue adds bias and scatter-stores into Q2/K2/V2 fragment layouts.
// ---------------------------------------------------------------------------
__global__ __launch_bounds__(128) void projm_kernel(const unsigned short* __restrict__ xfrag,
                                                    const unsigned short* __restrict__ wfrag,
                                                    const float* __restrict__ bq,
                                                    const float* __restrict__ bk,
                                                    const float* __restrict__ bv,
                                                    unsigned short* __restrict__ qarr,
                                                    unsigned short* __restrict__ karr,
                                                    unsigned short* __restrict__ varr) {
    int j    = blockIdx.x;            // 4b * 128nt * 5og = 2560
    int og   = j % 5;
    int nt   = (j / 5) & 127;
    int b    = j / 640;
    int lane = threadIdx.x & 63;
    int ot   = og * 2 + (threadIdx.x >> 6);   // 0..9

    const unsigned short* abase = wfrag + ((size_t)ot * 16 * 64 + lane) * 8;
    const unsigned short* bbase = xfrag + (((size_t)(b * 128 + nt) * 16) * 64 + lane) * 8;

    f32x16 acc;
    #pragma unroll
    for (int r = 0; r < 16; r++) acc[r] = 0.f;

    #pragma unroll
    for (int ks = 0; ks < 16; ks++) {
        bf16x8 af = *(const bf16x8*)(abase + (size_t)ks * 512);
        bf16x8 bf = *(const bf16x8*)(bbase + (size_t)ks * 512);
        acc = __builtin_amdgcn_mfma_f32_32x32x16_bf16(af, bf, acc, 0, 0, 0);
    }

    int l31 = lane & 31;
    int hi2 = lane >> 5;

    if (ot == 0) {
        unsigned short* qb = qarr + (size_t)b * (NP * 32);
        #pragma unroll
        for (int r = 0; r < 16; r++) {
            int o = (r & 3) + 8 * (r >> 2) + 4 * hi2;
            float v = acc[r] + bq[o] * L2E;
            size_t idx = (((size_t)nt * 2 + (o >> 4)) * 32 + l31) * 16 + ((o >> 3) & 1) * 8 + (o & 7);
            qb[idx] = f2bf(v);
        }
    } else if (ot == 1) {
        unsigned short* kb = karr + (size_t)b * (NP * 32);
        #pragma unroll
        for (int r = 0; r < 16; r++) {
            int o = (r & 3) + 8 * (r >> 2) + 4 * hi2;
            float v = acc[r] + bk[o];
            size_t idx = (((size_t)nt * 2 + (o >> 4)) * 32 + l31) * 16 + ((o >> 3) & 1) * 8 + (o & 7);
            kb[idx] = f2bf(v);
        }
    } else {
        unsigned short* vb = varr + (size_t)b * (CC * NP);
        int kc = nt, w2 = (l31 >> 4) & 1, hiv = (l31 >> 3) & 1, ev = l31 & 7;
        size_t base = (((size_t)kc * 2 + w2) * 8) * 32 * 16 + hiv * 8 + ev;
        #pragma unroll
        for (int r = 0; r < 16; r++) {
            int c = (ot - 2) * 32 + (r & 3) + 8 * (r >> 2) + 4 * hi2;
            float v = acc[r] + bv[c];
            size_t idx = base + ((size_t)(c >> 5) * 32 + (c & 31)) * 16;
            vb[idx] = f2bf(v);
        }
    }
}

// ---------------------------------------------------------------------------
// K3: swapped-operand 32x32 MFMA flash attention, FULL-CHANNEL waves +
// explicit load hoisting (R14, +10us) + cvt_pk P-pack + tree-sum (this round).
// ---------------------------------------------------------------------------
__global__ __launch_bounds__(256, 2) void flash32_kernel(const unsigned short* __restrict__ qarr,
                                                         const unsigned short* __restrict__ karr,
                                                         const unsigned short* __restrict__ varr,
                                                         float* __restrict__ att) {
    __shared__ float cacc[64][136];    // combine: one wave's 128 acc f32 per lane
    __shared__ float cml[64][2];       // combine: m, l per lane
    int t    = threadIdx.x;
    int lane = t & 63;
    int ks   = t >> 6;                 // 0..3 key quarter
    int j    = blockIdx.x;
    int b    = j & 3;                  // batch -> XCD pinning
    int qt   = j >> 2;                 // 0..127 q-tile (32 rows)

    const unsigned short* qb2 = qarr + (size_t)b * (NP * 32);
    const unsigned short* kb2 = karr + (size_t)b * (NP * 32);
    const unsigned short* vb2 = varr + (size_t)b * (CC * NP);

    int q  = lane & 31;
    int hi = lane >> 5;
    int lq16 = (q * 2 + hi) * 8;       // lane's 16B slot within a 1KB fragment block

    bf16x8 qf0 = *(const bf16x8*)(qb2 + (size_t)(qt * 2 + 0) * 512 + lq16);
    bf16x8 qf1 = *(const bf16x8*)(qb2 + (size_t)(qt * 2 + 1) * 512 + lq16);

    f32x16 acc[8];
    #pragma unroll
    for (int ct = 0; ct < 8; ct++)
        #pragma unroll
        for (int r = 0; r < 16; r++) acc[ct][r] = 0.f;
    float mrun = -3.0e38f, lrun = 0.f;

    const f32x16 z16 = {0.f,0.f,0.f,0.f,0.f,0.f,0.f,0.f,0.f,0.f,0.f,0.f,0.f,0.f,0.f,0.f};

    // ---- prologue: K frags for first chunk
    int kc0 = ks * 32;
    const unsigned short* kcp0 = kb2 + (size_t)kc0 * 1024 + lq16;
    bf16x8 kcur0 = *(const bf16x8*)(kcp0);
    bf16x8 kcur1 = *(const bf16x8*)(kcp0 + 512);

    for (int kci = 0; kci < 32; ++kci) {
        int kcidx = kc0 + kci;

        // ---- issue all 16 V loads for THIS chunk (consumed after softmax)
        const unsigned short* vcp = vb2 + ((size_t)kcidx * 16) * 512 + lq16;
        bf16x8 vf[16];
        #pragma unroll
        for (int i = 0; i < 16; i++)
            vf[i] = *(const bf16x8*)(vcp + (size_t)i * 512);

        // ---- issue K loads for NEXT chunk (consumed next iteration)
        int nid = (kci < 31) ? (kcidx + 1) : kcidx;
        const unsigned short* kn = kb2 + (size_t)nid * 1024 + lq16;
        bf16x8 kn0 = *(const bf16x8*)(kn);
        bf16x8 kn1 = *(const bf16x8*)(kn + 512);

        // ---- QK^T swapped (operands already in registers)
        f32x16 s = __builtin_amdgcn_mfma_f32_32x32x16_bf16(kcur0, qf0, z16, 0, 0, 0);
        s = __builtin_amdgcn_mfma_f32_32x32x16_bf16(kcur1, qf1, s, 0, 0, 0);

        // ---- in-lane max over 16 keys + 1 cross-half swap
        float m01 = fmaxf(s[0], s[1]),   m23 = fmaxf(s[2], s[3]);
        float m45 = fmaxf(s[4], s[5]),   m67 = fmaxf(s[6], s[7]);
        float m89 = fmaxf(s[8], s[9]),   mab = fmaxf(s[10], s[11]);
        float mcd = fmaxf(s[12], s[13]), mef = fmaxf(s[14], s[15]);
        float mx = fmaxf(fmaxf(fmaxf(m01, m23), fmaxf(m45, m67)),
                         fmaxf(fmaxf(m89, mab), fmaxf(mcd, mef)));
        mx = fmaxf(mx, __shfl_xor(mx, 32, 64));

        // ---- defer-max (T13, log2 domain)
        if (!__all(mx - mrun <= 11.5f)) {
            float mn = fmaxf(mrun, mx);
            float sc = exp2fast(mrun - mn);
            mrun = mn;
            lrun *= sc;
            #pragma unroll
            for (int ct = 0; ct < 8; ct++)
                #pragma unroll
                for (int r = 0; r < 16; r++) acc[ct][r] *= sc;
        }

        // ---- P = exp2(S^T - m): cvt_pk pack + depth-4 tree sum
        unsigned int pkr[8];
        float ps[8];
        #pragma unroll
        for (int r2 = 0; r2 < 8; r2++) {
            float p0 = exp2fast(s[2 * r2]     - mrun);
            float p1 = exp2fast(s[2 * r2 + 1] - mrun);
            ps[r2] = p0 + p1;
            pkr[r2] = pk2(p0, p1);
        }
        float s01 = ps[0] + ps[1], s23 = ps[2] + ps[3];
        float s45 = ps[4] + ps[5], s67 = ps[6] + ps[7];
        float ss = (s01 + s23) + (s45 + s67);
        ss += __shfl_xor(ss, 32, 64);
        lrun += ss;

        // ---- PV: V frags already in flight/registers
        #pragma unroll
        for (int w2 = 0; w2 < 2; w2++) {
            unsigned int a0 = pkr[4 * w2 + 0], a1 = pkr[4 * w2 + 1];
            unsigned int c0 = pkr[4 * w2 + 2], c1 = pkr[4 * w2 + 3];
            unsigned int sa0 = __shfl_xor(a0, 32, 64), sa1 = __shfl_xor(a1, 32, 64);
            unsigned int sc0 = __shfl_xor(c0, 32, 64), sc1 = __shfl_xor(c1, 32, 64);
            u32x4 fr;
            if (hi == 0) { fr[0] = a0;  fr[1] = a1;  fr[2] = sa0; fr[3] = sa1; }
            else         { fr[0] = sc0; fr[1] = sc1; fr[2] = c0;  fr[3] = c1;  }
            bf16x8 pf = __builtin_bit_cast(bf16x8, fr);
            #pragma unroll
            for (int ct = 0; ct < 8; ct++) {
                acc[ct] = __builtin_amdgcn_mfma_f32_32x32x16_bf16(vf[w2 * 8 + ct], pf, acc[ct], 0, 0, 0);
            }
        }

        kcur0 = kn0; kcur1 = kn1;
    }

    // ---- split-K combine: ks 3,2,1 hand state to ks 0 (elementwise per lane)
    for (int sIdx = 3; sIdx >= 1; --sIdx) {
        if (ks == sIdx) {
            #pragma unroll
            for (int ct = 0; ct < 8; ct++)
                #pragma unroll
                for (int rr = 0; rr < 4; rr++) {
                    float4 v4 = {acc[ct][rr*4+0], acc[ct][rr*4+1], acc[ct][rr*4+2], acc[ct][rr*4+3]};
                    *(float4*)&cacc[lane][ct * 16 + rr * 4] = v4;
                }
            cml[lane][0] = mrun; cml[lane][1] = lrun;
        }
        __syncthreads();
        if (ks == 0) {
            float mo = cml[lane][0];
            float lo = cml[lane][1];
            float mn = fmaxf(mrun, mo);
            float e0 = exp2fast(mrun - mn);
            float e1 = exp2fast(mo - mn);
            mrun = mn;
            lrun = lrun * e0 + lo * e1;
            #pragma unroll
            for (int ct = 0; ct < 8; ct++)
                #pragma unroll
                for (int r = 0; r < 16; r++)
                    acc[ct][r] = acc[ct][r] * e0 + cacc[lane][ct * 16 + r] * e1;
        }
        __syncthreads();
    }

    if (ks == 0) {
        float inv = 1.0f / lrun;
        #pragma unroll
        for (int ct = 0; ct < 8; ct++)
            #pragma unroll
            for (int r = 0; r < 16; r++) {
                int c = ct * 32 + (r & 3) + 8 * (r >> 2) + 4 * hi;
                att[((size_t)b * CC + c) * NP + qt * 32 + q] = acc[ct][r] * inv;
            }
    }
}

// ---------------------------------------------------------------------------
// K4: bilinear x2 upsample (half-pixel, edge clamp) + gamma * up + x, x4 vec
// ---------------------------------------------------------------------------
__global__ __launch_bounds__(256) void upsample_kernel(const float* __restrict__ att,
                                                       const float* __restrict__ x,
                                                       const float* __restrict__ gamma,
                                                       float* __restrict__ out) {
    int tid = blockIdx.x * 256 + threadIdx.x;    // B*C*H*W/4 threads
    int w4 = (tid & 31) * 4;
    int h  = (tid >> 5) & 127;
    int bc = tid >> 12;
    float g = gamma[0];

    float sh = 0.5f * h - 0.25f;
    float fhf = floorf(sh);
    float th = sh - fhf;
    int ih = (int)fhf;
    int ih0 = ih < 0 ? 0 : ih;
    int ih1 = ih + 1 > 63 ? 63 : ih + 1;
    const float* a0r = att + (size_t)bc * NP + ih0 * 64;
    const float* a1r = att + (size_t)bc * NP + ih1 * 64;

    float4 xin = *(const float4*)(x + (size_t)bc * (HH * WW) + h * WW + w4);
    float xv[4] = {xin.x, xin.y, xin.z, xin.w};
    float ov[4];
    #pragma unroll
    for (int k = 0; k < 4; k++) {
        int w = w4 + k;
        float sw = 0.5f * w - 0.25f;
        float fwf = floorf(sw);
        float tw = sw - fwf;
        int iw = (int)fwf;
        int iw0 = iw < 0 ? 0 : iw;
        int iw1 = iw + 1 > 63 ? 63 : iw + 1;
        float v00 = a0r[iw0], v01 = a0r[iw1];
        float v10 = a1r[iw0], v11 = a1r[iw1];
        float top = v00 + tw * (v01 - v00);
        float bot = v10 + tw * (v11 - v10);
        float up  = top + th * (bot - top);
        ov[k] = g * up + xv[k];
    }
    float4 o4 = {ov[0], ov[1], ov[2], ov[3]};
    *(float4*)(out + (size_t)bc * (HH * WW) + h * WW + w4) = o4;
}

// ---------------------------------------------------------------------------
extern "C" void kernel_launch(void* const* d_in, const int* in_sizes, int n_in,
                              void* d_out, int out_size, void* d_ws, size_t ws_size,
                              hipStream_t stream) {
    (void)in_sizes; (void)n_in; (void)out_size; (void)ws_size;
    const float* x     = (const float*)d_in[0];
    const float* wq    = (const float*)d_in[1];
    const float* bq    = (const float*)d_in[2];
    const float* wk    = (const float*)d_in[3];
    const float* bk    = (const float*)d_in[4];
    const float* wv    = (const float*)d_in[5];
    const float* bv    = (const float*)d_in[6];
    const float* gamma = (const float*)d_in[7];
    float* out = (float*)d_out;

    unsigned short* xfrag = (unsigned short*)d_ws;             // 4,194,304 u16 (8 MB)
    unsigned short* wfrag = xfrag + 4194304;                   // 81,920 u16 (pad to 131,072)
    unsigned short* qarr  = wfrag + 131072;                    // 524,288 u16 (1 MB)
    unsigned short* karr  = qarr + 524288;                     // 524,288 u16 (1 MB)
    unsigned short* varr  = karr + 524288;                     // 4,194,304 u16 (8 MB)
    float*          att   = (float*)(varr + 4194304);          // 4,194,304 f32 (16 MB)

    prep_kernel<<<2088, 256, 0, stream>>>(x, wq, wk, wv, xfrag, wfrag);
    projm_kernel<<<2560, 128, 0, stream>>>(xfrag, wfrag, bq, bk, bv, qarr, karr, varr);
    flash32_kernel<<<512, 256, 0, stream>>>(qarr, karr, varr, att);
    upsample_kernel<<<16384, 256, 0, stream>>>(att, x, gamma, out);
}